// Round 1
// baseline (788.484 us; speedup 1.0000x reference)
//
#include <hip/hip_runtime.h>
#include <math.h>

#define BB 4
#define LL 1024
#define RR 4
#define DD 1024
#define NHEADS 16
#define HDIM 64
#define FFD 4096
#define EPSV 1e-6f

typedef short s16x8 __attribute__((ext_vector_type(8)));
typedef float f32x4 __attribute__((ext_vector_type(4)));

__device__ inline unsigned short f2bf(float x) {
  unsigned u = __builtin_bit_cast(unsigned, x);
  unsigned r = (u + 0x7fffu + ((u >> 16) & 1u)) >> 16;
  return (unsigned short)r;
}

__device__ inline float wred_sum(float v) {
#pragma unroll
  for (int off = 32; off; off >>= 1) v += __shfl_down(v, off);
  return v;
}

// ---------------- f32 -> bf16 (as ushort bits) ----------------
__global__ __launch_bounds__(256) void cvt_bf16_kernel(const float* __restrict__ in,
                                                       unsigned short* __restrict__ out, int n4) {
  int stride = gridDim.x * 256;
  for (int i = blockIdx.x * 256 + threadIdx.x; i < n4; i += stride) {
    float4 v = ((const float4*)in)[i];
    ushort4 o;
    o.x = f2bf(v.x); o.y = f2bf(v.y); o.z = f2bf(v.z); o.w = f2bf(v.w);
    ((ushort4*)out)[i] = o;
  }
}

// ---------------- width (hyper-connection) kernel ----------------
// FUSED=false: Hs = Hin[bl]           (block = one (b,l))
// FUSED=true : Hs = beta_in*attnout + mixrest_in   (depth-1 fused)
// outputs: mixrest_out = mix[k=1..4], beta_out, x_out = bf16(RMS(mix0)*post_norm_w)
template<bool FUSED>
__global__ __launch_bounds__(256) void width_kernel(
    const float* __restrict__ Hin,
    const float* mixrest_in,           // may alias mixrest_out (reads complete first)
    const float* __restrict__ beta_in,
    const float* __restrict__ attnout,
    const float* __restrict__ hc_norm_w,
    const float* __restrict__ alpha_fn,   // [D,5]
    const float* __restrict__ beta_fn,    // [D]
    const float* __restrict__ a_scale,
    const float* __restrict__ b_scale,
    const float* __restrict__ s_alpha,    // [4,5]
    const float* __restrict__ s_beta,     // [4]
    const float* __restrict__ post_norm_w,
    float* mixrest_out,
    float* __restrict__ beta_out,
    unsigned short* __restrict__ x_out)
{
  const int bl = blockIdx.x;
  const int t = threadIdx.x;
  const int wid = t >> 6;
  __shared__ __align__(16) float Hs[4 * 1024];
  __shared__ __align__(16) float m0[1024];
  __shared__ float scr[96];
  __shared__ float alpha_s[4][5];
  __shared__ float beta_s[4];
  __shared__ float inv_s[4];
  __shared__ float inv0_s;

  if (FUSED) {
    ((float4*)m0)[t] = ((const float4*)(attnout + (size_t)bl * 1024))[t];
    __syncthreads();
    for (int i = t; i < 1024; i += 256) {
      int n = i >> 8;
      float be = beta_in[bl * 4 + n];
      float4 mr = ((const float4*)(mixrest_in + (size_t)bl * 4096))[i];
      float4 ao = ((const float4*)m0)[i & 255];
      float4 hv;
      hv.x = be * ao.x + mr.x; hv.y = be * ao.y + mr.y;
      hv.z = be * ao.z + mr.z; hv.w = be * ao.w + mr.w;
      ((float4*)Hs)[i] = hv;
    }
  } else {
    for (int i = t; i < 1024; i += 256)
      ((float4*)Hs)[i] = ((const float4*)(Hin + (size_t)bl * 4096))[i];
  }
  __syncthreads();

  // per-row sum of squares
  float ss[4];
#pragma unroll
  for (int n = 0; n < 4; ++n) {
    float a = 0.f;
    for (int d = t; d < 1024; d += 256) { float v = Hs[n * 1024 + d]; a += v * v; }
    ss[n] = a;
  }
#pragma unroll
  for (int n = 0; n < 4; ++n) {
    float r = wred_sum(ss[n]);
    if ((t & 63) == 0) scr[wid * 4 + n] = r;
  }
  __syncthreads();
  if (t < 4) {
    float tot = scr[t] + scr[4 + t] + scr[8 + t] + scr[12 + t];
    inv_s[t] = 1.f / (sqrtf(tot * (1.f / 1024.f)) + EPSV);
  }
  __syncthreads();
  float inv[4] = {inv_s[0], inv_s[1], inv_s[2], inv_s[3]};

  // 24 dot products: nh . alpha_fn[:,k] (k=0..4) and nh . beta_fn
  float dots[4][6];
#pragma unroll
  for (int n = 0; n < 4; ++n)
#pragma unroll
    for (int k = 0; k < 6; ++k) dots[n][k] = 0.f;
  for (int d = t; d < 1024; d += 256) {
    float w = hc_norm_w[d];
    float a0 = alpha_fn[d * 5 + 0], a1 = alpha_fn[d * 5 + 1], a2 = alpha_fn[d * 5 + 2],
          a3 = alpha_fn[d * 5 + 3], a4 = alpha_fn[d * 5 + 4];
    float bfv = beta_fn[d];
#pragma unroll
    for (int n = 0; n < 4; ++n) {
      float nh = Hs[n * 1024 + d] * w * inv[n];
      dots[n][0] += nh * a0; dots[n][1] += nh * a1; dots[n][2] += nh * a2;
      dots[n][3] += nh * a3; dots[n][4] += nh * a4; dots[n][5] += nh * bfv;
    }
  }
  __syncthreads();
#pragma unroll
  for (int n = 0; n < 4; ++n)
#pragma unroll
    for (int k = 0; k < 6; ++k) {
      float r = wred_sum(dots[n][k]);
      if ((t & 63) == 0) scr[wid * 24 + n * 6 + k] = r;
    }
  __syncthreads();
  if (t < 24) {
    float raw = scr[t] + scr[24 + t] + scr[48 + t] + scr[72 + t];
    int n = t / 6, k = t % 6;
    if (k < 5) alpha_s[n][k] = tanhf(raw) * a_scale[0] + s_alpha[n * 5 + k];
    else       beta_s[n]     = tanhf(raw) * b_scale[0] + s_beta[n];
  }
  __syncthreads();

  // mix[k][d] = sum_n alpha[n][k] * H[n][d]
  {
    int i = t;  // exactly 256 float4 per row of 1024
    float4 h0 = ((const float4*)Hs)[i];
    float4 h1 = ((const float4*)Hs)[256 + i];
    float4 h2 = ((const float4*)Hs)[512 + i];
    float4 h3 = ((const float4*)Hs)[768 + i];
#pragma unroll
    for (int k = 0; k < 5; ++k) {
      float c0 = alpha_s[0][k], c1 = alpha_s[1][k], c2 = alpha_s[2][k], c3 = alpha_s[3][k];
      float4 mv;
      mv.x = c0 * h0.x + c1 * h1.x + c2 * h2.x + c3 * h3.x;
      mv.y = c0 * h0.y + c1 * h1.y + c2 * h2.y + c3 * h3.y;
      mv.z = c0 * h0.z + c1 * h1.z + c2 * h2.z + c3 * h3.z;
      mv.w = c0 * h0.w + c1 * h1.w + c2 * h2.w + c3 * h3.w;
      if (k == 0) ((float4*)m0)[i] = mv;
      else ((float4*)(mixrest_out + (size_t)bl * 4096 + (size_t)(k - 1) * 1024))[i] = mv;
    }
  }
  if (t < 4) beta_out[bl * 4 + t] = beta_s[t];
  __syncthreads();

  // RMS(mix0) * post_norm_w -> x_out (bf16)
  {
    float a = 0.f;
    for (int d = t; d < 1024; d += 256) { float v = m0[d]; a += v * v; }
    float r = wred_sum(a);
    if ((t & 63) == 0) scr[wid] = r;
  }
  __syncthreads();
  if (t == 0) {
    float tot = scr[0] + scr[1] + scr[2] + scr[3];
    inv0_s = 1.f / (sqrtf(tot * (1.f / 1024.f)) + EPSV);
  }
  __syncthreads();
  {
    float iv = inv0_s;
    float4 mv = ((const float4*)m0)[t];
    float4 wv = ((const float4*)post_norm_w)[t];
    ushort4 ov;
    ov.x = f2bf(wv.x * mv.x * iv);
    ov.y = f2bf(wv.y * mv.y * iv);
    ov.z = f2bf(wv.z * mv.z * iv);
    ov.w = f2bf(wv.w * mv.w * iv);
    ((ushort4*)(x_out + (size_t)bl * 1024))[t] = ov;
  }
}

// ---------------- bf16 GEMM: C[M,N] = A[M,K] @ W[N,K]^T ----------------
// EPI=0: store f32; EPI=1: gelu(exact) -> bf16
template<int EPI>
__global__ __launch_bounds__(256) void gemm_bt_kernel(
    const unsigned short* __restrict__ A,
    const unsigned short* __restrict__ W,
    float* __restrict__ Cf, unsigned short* __restrict__ Cb,
    int M, int N, int K)
{
  __shared__ __align__(16) unsigned short As[128 * 32];
  __shared__ __align__(16) unsigned short Bs[128 * 32];
  const int tn = N >> 7;
  const int bm = blockIdx.x / tn, bn = blockIdx.x % tn;
  const int t = threadIdx.x, lane = t & 63, wid = t >> 6;
  const int wr = wid >> 1, wc = wid & 1;
  const int m0 = bm << 7, n0 = bn << 7;
  const int srow = t >> 2, scol = (t & 3) << 3;
  const int fr = lane & 15, fks = (lane >> 4) << 3;

  f32x4 acc[4][4];
#pragma unroll
  for (int i = 0; i < 4; ++i)
#pragma unroll
    for (int j = 0; j < 4; ++j)
#pragma unroll
      for (int e = 0; e < 4; ++e) acc[i][j][e] = 0.f;

  for (int k0 = 0; k0 < K; k0 += 32) {
    s16x8 av0 = *(const s16x8*)(A + (size_t)(m0 + srow) * K + k0 + scol);
    s16x8 av1 = *(const s16x8*)(A + (size_t)(m0 + 64 + srow) * K + k0 + scol);
    s16x8 bv0 = *(const s16x8*)(W + (size_t)(n0 + srow) * K + k0 + scol);
    s16x8 bv1 = *(const s16x8*)(W + (size_t)(n0 + 64 + srow) * K + k0 + scol);
    __syncthreads();
    *(s16x8*)(As + srow * 32 + scol) = av0;
    *(s16x8*)(As + (64 + srow) * 32 + scol) = av1;
    *(s16x8*)(Bs + srow * 32 + scol) = bv0;
    *(s16x8*)(Bs + (64 + srow) * 32 + scol) = bv1;
    __syncthreads();
    s16x8 af[4], bfr[4];
#pragma unroll
    for (int m = 0; m < 4; ++m)
      af[m] = *(const s16x8*)(As + (wr * 64 + m * 16 + fr) * 32 + fks);
#pragma unroll
    for (int n = 0; n < 4; ++n)
      bfr[n] = *(const s16x8*)(Bs + (wc * 64 + n * 16 + fr) * 32 + fks);
#pragma unroll
    for (int m = 0; m < 4; ++m)
#pragma unroll
      for (int n = 0; n < 4; ++n)
        acc[m][n] = __builtin_amdgcn_mfma_f32_16x16x32_bf16(af[m], bfr[n], acc[m][n], 0, 0, 0);
  }

  const int rb = m0 + wr * 64 + ((lane >> 4) << 2);
  const int cb = n0 + wc * 64 + (lane & 15);
#pragma unroll
  for (int m = 0; m < 4; ++m)
#pragma unroll
    for (int n = 0; n < 4; ++n)
#pragma unroll
      for (int j = 0; j < 4; ++j) {
        int r = rb + m * 16 + j;
        int c = cb + n * 16;
        float v = acc[m][n][j];
        if (EPI == 1) {
          v = 0.5f * v * (1.f + erff(v * 0.70710678118f));
          Cb[(size_t)r * N + c] = f2bf(v);
        } else {
          Cf[(size_t)r * N + c] = v;
        }
      }
}

// ---------------- flash attention (fp32 VALU), causal ----------------
// grid: (L/16, HEADS, B); 16 q-rows per block; qkv: [B*L, 3072] f32
__global__ __launch_bounds__(256) void attn_kernel(
    const float* __restrict__ qkv, unsigned short* __restrict__ out)
{
  const int qt = blockIdx.x, h = blockIdx.y, b = blockIdx.z;
  __shared__ __align__(16) float Qs[16][68];
  __shared__ __align__(16) float Ks[64][68];
  __shared__ __align__(16) float Vs[64][68];
  __shared__ __align__(16) float Ps[16][64];
  const int t = threadIdx.x;
  const int qi = t >> 4, c = t & 15;
  const int q0 = qt << 4;
  const size_t rowbase = (size_t)(b * LL) * 3072 + h * 64;

  for (int i = t; i < 256; i += 256) {
    int r = i >> 4, d4 = (i & 15) * 4;
    *(float4*)&Qs[r][d4] = *(const float4*)&qkv[rowbase + (size_t)(q0 + r) * 3072 + d4];
  }
  __syncthreads();
  float4 qreg[16];
#pragma unroll
  for (int x = 0; x < 16; ++x) qreg[x] = *(const float4*)&Qs[qi][x * 4];

  float4 o4; o4.x = 0.f; o4.y = 0.f; o4.z = 0.f; o4.w = 0.f;
  float m_i = -INFINITY, l_i = 0.f;
  const int qg = q0 + qi;
  const int nkt = (q0 + 16 + 63) >> 6;

  for (int kt = 0; kt < nkt; ++kt) {
    __syncthreads();
    const int kb = kt << 6;
    for (int i = t; i < 1024; i += 256) {
      int r = i >> 4, d4 = (i & 15) * 4;
      size_t g = rowbase + (size_t)(kb + r) * 3072 + d4;
      *(float4*)&Ks[r][d4] = *(const float4*)&qkv[g + 1024];
      *(float4*)&Vs[r][d4] = *(const float4*)&qkv[g + 2048];
    }
    __syncthreads();

    float s[4], mloc = -INFINITY;
#pragma unroll
    for (int jj = 0; jj < 4; ++jj) {
      const int j = c + (jj << 4);
      const float4* kr = (const float4*)&Ks[j][0];
      float acc = 0.f;
#pragma unroll
      for (int x = 0; x < 16; ++x) {
        float4 kv = kr[x];
        acc += qreg[x].x * kv.x + qreg[x].y * kv.y + qreg[x].z * kv.z + qreg[x].w * kv.w;
      }
      s[jj] = (kb + j <= qg) ? acc * 0.125f : -INFINITY;
      mloc = fmaxf(mloc, s[jj]);
    }
#pragma unroll
    for (int off = 8; off; off >>= 1) mloc = fmaxf(mloc, __shfl_xor(mloc, off, 16));
    const float m_new = fmaxf(m_i, mloc);
    const float fac = expf(m_i - m_new);
    float lloc = 0.f;
#pragma unroll
    for (int jj = 0; jj < 4; ++jj) {
      float p = expf(s[jj] - m_new);
      Ps[qi][c + (jj << 4)] = p;
      lloc += p;
    }
#pragma unroll
    for (int off = 8; off; off >>= 1) lloc += __shfl_xor(lloc, off, 16);
    l_i = l_i * fac + lloc;
    m_i = m_new;
    __syncthreads();

    o4.x *= fac; o4.y *= fac; o4.z *= fac; o4.w *= fac;
    const float4* pr = (const float4*)&Ps[qi][0];
#pragma unroll 4
    for (int j4 = 0; j4 < 16; ++j4) {
      float4 p4 = pr[j4];
      float4 v;
      v = *(const float4*)&Vs[4 * j4 + 0][c * 4];
      o4.x += p4.x * v.x; o4.y += p4.x * v.y; o4.z += p4.x * v.z; o4.w += p4.x * v.w;
      v = *(const float4*)&Vs[4 * j4 + 1][c * 4];
      o4.x += p4.y * v.x; o4.y += p4.y * v.y; o4.z += p4.y * v.z; o4.w += p4.y * v.w;
      v = *(const float4*)&Vs[4 * j4 + 2][c * 4];
      o4.x += p4.z * v.x; o4.y += p4.z * v.y; o4.z += p4.z * v.z; o4.w += p4.z * v.w;
      v = *(const float4*)&Vs[4 * j4 + 3][c * 4];
      o4.x += p4.w * v.x; o4.y += p4.w * v.y; o4.z += p4.w * v.z; o4.w += p4.w * v.w;
    }
  }
  const float invl = 1.f / l_i;
  ushort4 ov;
  ov.x = f2bf(o4.x * invl); ov.y = f2bf(o4.y * invl);
  ov.z = f2bf(o4.z * invl); ov.w = f2bf(o4.w * invl);
  *(ushort4*)(out + (size_t)(b * LL + qg) * 1024 + h * 64 + c * 4) = ov;
}

// ---------------- final depth-2 ----------------
__global__ __launch_bounds__(256) void depth2_kernel(
    const float* __restrict__ ffnout, const float* __restrict__ mixrest,
    const float* __restrict__ beta, float* __restrict__ Hout)
{
  const size_t stride = (size_t)gridDim.x * 256;
  const size_t n4 = (size_t)BB * LL * RR * DD / 4;
  for (size_t i = (size_t)blockIdx.x * 256 + threadIdx.x; i < n4; i += stride) {
    size_t e = i * 4;
    int d = (int)(e & 1023);
    int n = (int)((e >> 10) & 3);
    size_t bl = e >> 12;
    float be = beta[bl * 4 + n];
    float4 f = *(const float4*)&ffnout[bl * 1024 + d];
    float4 m = ((const float4*)mixrest)[i];
    float4 o;
    o.x = be * f.x + m.x; o.y = be * f.y + m.y;
    o.z = be * f.z + m.z; o.w = be * f.w + m.w;
    ((float4*)Hout)[i] = o;
  }
}

extern "C" void kernel_launch(void* const* d_in, const int* in_sizes, int n_in,
                              void* d_out, int out_size, void* d_ws, size_t ws_size,
                              hipStream_t stream) {
  const float* H       = (const float*)d_in[0];
  const float* hc1_nw  = (const float*)d_in[1];
  const float* hc1_afn = (const float*)d_in[2];
  const float* hc1_bfn = (const float*)d_in[3];
  const float* hc1_as  = (const float*)d_in[4];
  const float* hc1_bs  = (const float*)d_in[5];
  const float* hc1_sa  = (const float*)d_in[6];
  const float* hc1_sb  = (const float*)d_in[7];
  const float* attn_nw = (const float*)d_in[8];
  const float* qkv_w   = (const float*)d_in[9];
  const float* out_w   = (const float*)d_in[10];
  const float* hc2_nw  = (const float*)d_in[11];
  const float* hc2_afn = (const float*)d_in[12];
  const float* hc2_bfn = (const float*)d_in[13];
  const float* hc2_as  = (const float*)d_in[14];
  const float* hc2_bs  = (const float*)d_in[15];
  const float* hc2_sa  = (const float*)d_in[16];
  const float* hc2_sb  = (const float*)d_in[17];
  const float* ffn_nw  = (const float*)d_in[18];
  const float* fc1_w   = (const float*)d_in[19];
  const float* fc2_w   = (const float*)d_in[20];
  float* Hout = (float*)d_out;

  char* wsp = (char*)d_ws;
  size_t off = 0;
  auto carve = [&](size_t bytes) {
    void* p = wsp + off;
    off = (off + bytes + 255) & ~(size_t)255;
    return p;
  };
  unsigned short* wq_bf = (unsigned short*)carve((size_t)3072 * 1024 * 2);
  unsigned short* wo_bf = (unsigned short*)carve((size_t)1024 * 1024 * 2);
  unsigned short* w1_bf = (unsigned short*)carve((size_t)4096 * 1024 * 2);
  unsigned short* w2_bf = (unsigned short*)carve((size_t)4096 * 1024 * 2);
  unsigned short* xbf   = (unsigned short*)carve((size_t)4096 * 1024 * 2);
  float* mixrest        = (float*)carve((size_t)4096 * 4096 * 4);
  float* beta1          = (float*)carve((size_t)16384 * 4);
  float* beta2          = (float*)carve((size_t)16384 * 4);
  float* qkvf           = (float*)carve((size_t)4096 * 3072 * 4);
  unsigned short* g1_bf = (unsigned short*)qkvf;  // alias: qkv dead after attention
  unsigned short* attn_bf = (unsigned short*)carve((size_t)4096 * 1024 * 2);
  float* aof            = (float*)carve((size_t)4096 * 1024 * 4);  // attnout / ffnout

  // 1. weights -> bf16
  cvt_bf16_kernel<<<1024, 256, 0, stream>>>(qkv_w, wq_bf, 3072 * 1024 / 4);
  cvt_bf16_kernel<<<512, 256, 0, stream>>>(out_w, wo_bf, 1024 * 1024 / 4);
  cvt_bf16_kernel<<<1024, 256, 0, stream>>>(fc1_w, w1_bf, 4096 * 1024 / 4);
  cvt_bf16_kernel<<<1024, 256, 0, stream>>>(fc2_w, w2_bf, 4096 * 1024 / 4);
  // 2. width1 (+ pre-attn RMS)
  width_kernel<false><<<4096, 256, 0, stream>>>(H, nullptr, nullptr, nullptr,
      hc1_nw, hc1_afn, hc1_bfn, hc1_as, hc1_bs, hc1_sa, hc1_sb, attn_nw,
      mixrest, beta1, xbf);
  // 3. qkv
  gemm_bt_kernel<0><<<32 * 24, 256, 0, stream>>>(xbf, wq_bf, qkvf, nullptr, 4096, 3072, 1024);
  // 4. attention
  attn_kernel<<<dim3(64, 16, 4), 256, 0, stream>>>(qkvf, attn_bf);
  // 5. out projection
  gemm_bt_kernel<0><<<32 * 8, 256, 0, stream>>>(attn_bf, wo_bf, aof, nullptr, 4096, 1024, 1024);
  // 6. depth1 + width2 (+ pre-ffn RMS); mixrest in-place
  width_kernel<true><<<4096, 256, 0, stream>>>(nullptr, mixrest, beta1, aof,
      hc2_nw, hc2_afn, hc2_bfn, hc2_as, hc2_bs, hc2_sa, hc2_sb, ffn_nw,
      mixrest, beta2, xbf);
  // 7. fc1 + gelu -> bf16
  gemm_bt_kernel<1><<<32 * 32, 256, 0, stream>>>(xbf, w1_bf, nullptr, g1_bf, 4096, 4096, 1024);
  // 8. fc2
  gemm_bt_kernel<0><<<32 * 8, 256, 0, stream>>>(g1_bf, w2_bf, aof, nullptr, 4096, 1024, 4096);
  // 9. depth2 -> output
  depth2_kernel<<<4096, 256, 0, stream>>>(aof, mixrest, beta2, Hout);
}

// Round 2
// 454.950 us; speedup vs baseline: 1.7331x; 1.7331x over previous
//
#include <hip/hip_runtime.h>
#include <math.h>

#define BB 4
#define LL 1024
#define RR 4
#define DD 1024
#define NHEADS 16
#define HDIM 64
#define FFD 4096
#define EPSV 1e-6f

typedef short s16x8 __attribute__((ext_vector_type(8)));
typedef float f32x4 __attribute__((ext_vector_type(4)));
typedef unsigned short u16;

__device__ inline unsigned short f2bf(float x) {
  unsigned u = __builtin_bit_cast(unsigned, x);
  unsigned r = (u + 0x7fffu + ((u >> 16) & 1u)) >> 16;
  return (unsigned short)r;
}

__device__ inline float wred_sum(float v) {
#pragma unroll
  for (int off = 32; off; off >>= 1) v += __shfl_down(v, off);
  return v;
}

__device__ inline void gload_lds16(const u16* g, u16* l) {
  __builtin_amdgcn_global_load_lds(
      (const __attribute__((address_space(1))) unsigned int*)g,
      (__attribute__((address_space(3))) unsigned int*)l, 16, 0, 0);
}

// ---------------- f32 -> bf16 ----------------
__global__ __launch_bounds__(256) void cvt_bf16_kernel(const float* __restrict__ in,
                                                       u16* __restrict__ out, int n4) {
  int stride = gridDim.x * 256;
  for (int i = blockIdx.x * 256 + threadIdx.x; i < n4; i += stride) {
    float4 v = ((const float4*)in)[i];
    ushort4 o;
    o.x = f2bf(v.x); o.y = f2bf(v.y); o.z = f2bf(v.z); o.w = f2bf(v.w);
    ((ushort4*)out)[i] = o;
  }
}

// ---------------- width (hyper-connection) kernel ----------------
template<bool FUSED>
__global__ __launch_bounds__(256) void width_kernel(
    const float* __restrict__ Hin,
    const float* mixrest_in,
    const float* __restrict__ beta_in,
    const float* __restrict__ attnout,
    const float* __restrict__ hc_norm_w,
    const float* __restrict__ alpha_fn,
    const float* __restrict__ beta_fn,
    const float* __restrict__ a_scale,
    const float* __restrict__ b_scale,
    const float* __restrict__ s_alpha,
    const float* __restrict__ s_beta,
    const float* __restrict__ post_norm_w,
    float* mixrest_out,
    float* __restrict__ beta_out,
    u16* __restrict__ x_out)
{
  const int bl = blockIdx.x;
  const int t = threadIdx.x;
  const int wid = t >> 6;
  __shared__ __align__(16) float Hs[4 * 1024];
  __shared__ __align__(16) float m0[1024];
  __shared__ float scr[96];
  __shared__ float alpha_s[4][5];
  __shared__ float beta_s[4];
  __shared__ float inv_s[4];
  __shared__ float inv0_s;

  if (FUSED) {
    ((float4*)m0)[t] = ((const float4*)(attnout + (size_t)bl * 1024))[t];
    __syncthreads();
    for (int i = t; i < 1024; i += 256) {
      int n = i >> 8;
      float be = beta_in[bl * 4 + n];
      float4 mr = ((const float4*)(mixrest_in + (size_t)bl * 4096))[i];
      float4 ao = ((const float4*)m0)[i & 255];
      float4 hv;
      hv.x = be * ao.x + mr.x; hv.y = be * ao.y + mr.y;
      hv.z = be * ao.z + mr.z; hv.w = be * ao.w + mr.w;
      ((float4*)Hs)[i] = hv;
    }
  } else {
    for (int i = t; i < 1024; i += 256)
      ((float4*)Hs)[i] = ((const float4*)(Hin + (size_t)bl * 4096))[i];
  }
  __syncthreads();

  float ss[4];
#pragma unroll
  for (int n = 0; n < 4; ++n) {
    float a = 0.f;
    for (int d = t; d < 1024; d += 256) { float v = Hs[n * 1024 + d]; a += v * v; }
    ss[n] = a;
  }
#pragma unroll
  for (int n = 0; n < 4; ++n) {
    float r = wred_sum(ss[n]);
    if ((t & 63) == 0) scr[wid * 4 + n] = r;
  }
  __syncthreads();
  if (t < 4) {
    float tot = scr[t] + scr[4 + t] + scr[8 + t] + scr[12 + t];
    inv_s[t] = 1.f / (sqrtf(tot * (1.f / 1024.f)) + EPSV);
  }
  __syncthreads();
  float inv[4] = {inv_s[0], inv_s[1], inv_s[2], inv_s[3]};

  float dots[4][6];
#pragma unroll
  for (int n = 0; n < 4; ++n)
#pragma unroll
    for (int k = 0; k < 6; ++k) dots[n][k] = 0.f;
  for (int d = t; d < 1024; d += 256) {
    float w = hc_norm_w[d];
    float a0 = alpha_fn[d * 5 + 0], a1 = alpha_fn[d * 5 + 1], a2 = alpha_fn[d * 5 + 2],
          a3 = alpha_fn[d * 5 + 3], a4 = alpha_fn[d * 5 + 4];
    float bfv = beta_fn[d];
#pragma unroll
    for (int n = 0; n < 4; ++n) {
      float nh = Hs[n * 1024 + d] * w * inv[n];
      dots[n][0] += nh * a0; dots[n][1] += nh * a1; dots[n][2] += nh * a2;
      dots[n][3] += nh * a3; dots[n][4] += nh * a4; dots[n][5] += nh * bfv;
    }
  }
  __syncthreads();
#pragma unroll
  for (int n = 0; n < 4; ++n)
#pragma unroll
    for (int k = 0; k < 6; ++k) {
      float r = wred_sum(dots[n][k]);
      if ((t & 63) == 0) scr[wid * 24 + n * 6 + k] = r;
    }
  __syncthreads();
  if (t < 24) {
    float raw = scr[t] + scr[24 + t] + scr[48 + t] + scr[72 + t];
    int n = t / 6, k = t % 6;
    if (k < 5) alpha_s[n][k] = tanhf(raw) * a_scale[0] + s_alpha[n * 5 + k];
    else       beta_s[n]     = tanhf(raw) * b_scale[0] + s_beta[n];
  }
  __syncthreads();

  {
    int i = t;
    float4 h0 = ((const float4*)Hs)[i];
    float4 h1 = ((const float4*)Hs)[256 + i];
    float4 h2 = ((const float4*)Hs)[512 + i];
    float4 h3 = ((const float4*)Hs)[768 + i];
#pragma unroll
    for (int k = 0; k < 5; ++k) {
      float c0 = alpha_s[0][k], c1 = alpha_s[1][k], c2 = alpha_s[2][k], c3 = alpha_s[3][k];
      float4 mv;
      mv.x = c0 * h0.x + c1 * h1.x + c2 * h2.x + c3 * h3.x;
      mv.y = c0 * h0.y + c1 * h1.y + c2 * h2.y + c3 * h3.y;
      mv.z = c0 * h0.z + c1 * h1.z + c2 * h2.z + c3 * h3.z;
      mv.w = c0 * h0.w + c1 * h1.w + c2 * h2.w + c3 * h3.w;
      if (k == 0) ((float4*)m0)[i] = mv;
      else ((float4*)(mixrest_out + (size_t)bl * 4096 + (size_t)(k - 1) * 1024))[i] = mv;
    }
  }
  if (t < 4) beta_out[bl * 4 + t] = beta_s[t];
  __syncthreads();

  {
    float a = 0.f;
    for (int d = t; d < 1024; d += 256) { float v = m0[d]; a += v * v; }
    float r = wred_sum(a);
    if ((t & 63) == 0) scr[wid] = r;
  }
  __syncthreads();
  if (t == 0) {
    float tot = scr[0] + scr[1] + scr[2] + scr[3];
    inv0_s = 1.f / (sqrtf(tot * (1.f / 1024.f)) + EPSV);
  }
  __syncthreads();
  {
    float iv = inv0_s;
    float4 mv = ((const float4*)m0)[t];
    float4 wv = ((const float4*)post_norm_w)[t];
    ushort4 ov;
    ov.x = f2bf(wv.x * mv.x * iv);
    ov.y = f2bf(wv.y * mv.y * iv);
    ov.z = f2bf(wv.z * mv.z * iv);
    ov.w = f2bf(wv.w * mv.w * iv);
    ((ushort4*)(x_out + (size_t)bl * 1024))[t] = ov;
  }
}

// ---------------- bf16 GEMM: C[M,N] = A[M,K] @ W[N,K]^T ----------------
// EPI=0: f32 out; EPI=1: gelu->bf16; EPI=2: qkv split (Q,K bf16 [M,2048], V transposed)
template<int EPI>
__global__ __launch_bounds__(256) void gemm_bt_kernel(
    const u16* __restrict__ A, const u16* __restrict__ W,
    float* __restrict__ Cf, u16* __restrict__ Cb, u16* __restrict__ Vt,
    int M, int N, int K)
{
  __shared__ __align__(16) u16 As[128 * 32];
  __shared__ __align__(16) u16 Bs[128 * 32];
  const int tn = N >> 7;
  const int bm = blockIdx.x / tn, bn = blockIdx.x % tn;
  const int t = threadIdx.x, l = t & 63, w = t >> 6;
  const int wr = w >> 1, wc = w & 1;
  const int m0 = bm << 7, n0 = bn << 7;
  // staging: wave w covers rows [w*32, w*32+32); lane: row (l>>2), dest chunk (l&3)
  // pre-swizzled source chunk = (l&3) ^ (row&3)  -> LDS (row, dc) holds global chunk dc^(row&3)
  const int ssc = (((l & 3) ^ ((l >> 2) & 3)) << 3);
  const int srA = m0 + (w << 5) + (l >> 2);
  const int srB = n0 + (w << 5) + (l >> 2);
  u16* ldsA = As + (w << 10);
  u16* ldsB = Bs + (w << 10);
  const int fr = l & 15;
  const int fc8 = (((l >> 4) ^ (l & 3)) << 3);  // swizzled frag chunk (R&3 == l&3)

  f32x4 acc[4][4];
#pragma unroll
  for (int i = 0; i < 4; ++i)
#pragma unroll
    for (int j = 0; j < 4; ++j)
#pragma unroll
      for (int e = 0; e < 4; ++e) acc[i][j][e] = 0.f;

  const u16* pa0 = A + (size_t)srA * K + ssc;
  const u16* pa1 = A + (size_t)(srA + 16) * K + ssc;
  const u16* pb0 = W + (size_t)srB * K + ssc;
  const u16* pb1 = W + (size_t)(srB + 16) * K + ssc;

  for (int k0 = 0; k0 < K; k0 += 32) {
    __syncthreads();
    gload_lds16(pa0 + k0, ldsA);
    gload_lds16(pa1 + k0, ldsA + 512);
    gload_lds16(pb0 + k0, ldsB);
    gload_lds16(pb1 + k0, ldsB + 512);
    __syncthreads();
    s16x8 af[4], bfr[4];
#pragma unroll
    for (int m = 0; m < 4; ++m)
      af[m] = *(const s16x8*)(As + (wr * 64 + m * 16 + fr) * 32 + fc8);
#pragma unroll
    for (int n = 0; n < 4; ++n)
      bfr[n] = *(const s16x8*)(Bs + (wc * 64 + n * 16 + fr) * 32 + fc8);
#pragma unroll
    for (int m = 0; m < 4; ++m)
#pragma unroll
      for (int n = 0; n < 4; ++n)
        acc[m][n] = __builtin_amdgcn_mfma_f32_16x16x32_bf16(af[m], bfr[n], acc[m][n], 0, 0, 0);
  }

  const int rb = m0 + wr * 64 + ((l >> 4) << 2);
  const int cb = n0 + wc * 64 + fr;
#pragma unroll
  for (int m = 0; m < 4; ++m)
#pragma unroll
    for (int n = 0; n < 4; ++n)
#pragma unroll
      for (int j = 0; j < 4; ++j) {
        int r = rb + m * 16 + j;
        int c = cb + n * 16;
        float v = acc[m][n][j];
        if (EPI == 1) {
          v = 0.5f * v * (1.f + erff(v * 0.70710678118f));
          Cb[(size_t)r * N + c] = f2bf(v);
        } else if (EPI == 2) {
          if (n0 < 2048) {
            Cb[(size_t)r * 2048 + c] = f2bf(v);
          } else {
            int cc = c - 2048;
            int hh = cc >> 6, dd = cc & 63;
            Vt[((size_t)((r >> 10) * 16 + hh) * 64 + dd) * 1024 + (r & 1023)] = f2bf(v);
          }
        } else {
          Cf[(size_t)r * N + c] = v;
        }
      }
}

// ---------------- MFMA flash attention, causal ----------------
// qk: [B*L][2048] bf16 (Q at h*64, K at 1024+h*64); Vt: [B*16][64][1024] bf16 (d-major)
// grid (16, 16, 4); 64 q-rows per block, 4 waves x 16 rows
__global__ __launch_bounds__(256) void attn_mfma_kernel(
    const u16* __restrict__ qk, const u16* __restrict__ Vt, u16* __restrict__ out)
{
  const int h = blockIdx.y, b = blockIdx.z;
  const int qt = (h & 1) ? (15 - blockIdx.x) : blockIdx.x;  // balance causal work per CU
  const int t = threadIdx.x, l = t & 63, w = t >> 6;
  const int q0 = qt << 6;
  __shared__ __align__(16) u16 Ks[64 * 64];
  __shared__ __align__(16) u16 Vs[64 * 64];
  __shared__ __align__(16) u16 Ps[4][16 * 64];

  const int fr = l & 15;
  const int fg = (l >> 4) << 3;
  const int fswz = (fr & 7) << 3;

  // Q frags (A layout): row l&15, d-chunk (l>>4)*8 (+32)
  const int qrow = q0 + w * 16 + fr;
  const size_t qbase = (size_t)(b * 1024 + qrow) * 2048 + h * 64 + fg;
  const s16x8 aq0 = *(const s16x8*)(qk + qbase);
  const s16x8 aq1 = *(const s16x8*)(qk + qbase + 32);

  f32x4 acc_o[4];
#pragma unroll
  for (int i = 0; i < 4; ++i)
#pragma unroll
    for (int e = 0; e < 4; ++e) acc_o[i][e] = 0.f;
  float m_i[4] = {-INFINITY, -INFINITY, -INFINITY, -INFINITY};
  float l_i[4] = {0.f, 0.f, 0.f, 0.f};

  const int srow = t >> 2;
  const int sc = (t & 3) << 4;
  const int c0s = sc ^ ((srow & 7) << 3);
  const int c1s = (sc + 8) ^ ((srow & 7) << 3);
  const int qrow_c = q0 + w * 16 + ((l >> 4) << 2);  // C-layout row base
  u16* Psw = &Ps[w][0];
  const int nkt = qt + 1;

  for (int kt = 0; kt < nkt; ++kt) {
    const int kb = kt << 6;
    __syncthreads();
    {
      size_t kg = (size_t)(b * 1024 + kb + srow) * 2048 + 1024 + h * 64 + sc;
      s16x8 kv0 = *(const s16x8*)(qk + kg);
      s16x8 kv1 = *(const s16x8*)(qk + kg + 8);
      size_t vg = (size_t)((b * 16 + h) * 64 + srow) * 1024 + kb + sc;
      s16x8 vv0 = *(const s16x8*)(Vt + vg);
      s16x8 vv1 = *(const s16x8*)(Vt + vg + 8);
      *(s16x8*)(Ks + srow * 64 + c0s) = kv0;
      *(s16x8*)(Ks + srow * 64 + c1s) = kv1;
      *(s16x8*)(Vs + srow * 64 + c0s) = vv0;
      *(s16x8*)(Vs + srow * 64 + c1s) = vv1;
    }
    __syncthreads();

    // QK^T: S[16q x 64k] per wave
    f32x4 s[4];
#pragma unroll
    for (int n = 0; n < 4; ++n) {
#pragma unroll
      for (int e = 0; e < 4; ++e) s[n][e] = 0.f;
      s16x8 bk0 = *(const s16x8*)(Ks + (n * 16 + fr) * 64 + (fg ^ fswz));
      s16x8 bk1 = *(const s16x8*)(Ks + (n * 16 + fr) * 64 + ((32 + fg) ^ fswz));
      s[n] = __builtin_amdgcn_mfma_f32_16x16x32_bf16(aq0, bk0, s[n], 0, 0, 0);
      s[n] = __builtin_amdgcn_mfma_f32_16x16x32_bf16(aq1, bk1, s[n], 0, 0, 0);
    }
#pragma unroll
    for (int n = 0; n < 4; ++n)
#pragma unroll
      for (int e = 0; e < 4; ++e) s[n][e] *= 0.125f;
    if (kt == qt) {
#pragma unroll
      for (int n = 0; n < 4; ++n) {
        int kc = kb + n * 16 + fr;
#pragma unroll
        for (int r = 0; r < 4; ++r)
          if (kc > qrow_c + r) s[n][r] = -INFINITY;
      }
    }

    // online softmax (4 rows per lane, replicated across 16-lane groups)
    float rm[4], fac[4];
#pragma unroll
    for (int r = 0; r < 4; ++r)
      rm[r] = fmaxf(fmaxf(s[0][r], s[1][r]), fmaxf(s[2][r], s[3][r]));
#pragma unroll
    for (int off = 1; off < 16; off <<= 1)
#pragma unroll
      for (int r = 0; r < 4; ++r) rm[r] = fmaxf(rm[r], __shfl_xor(rm[r], off));
#pragma unroll
    for (int r = 0; r < 4; ++r) {
      float mn = fmaxf(m_i[r], rm[r]);
      fac[r] = __expf(m_i[r] - mn);
      m_i[r] = mn;
    }
    float rs[4] = {0.f, 0.f, 0.f, 0.f};
    float pb[4][4];
#pragma unroll
    for (int n = 0; n < 4; ++n)
#pragma unroll
      for (int r = 0; r < 4; ++r) {
        float pv = __expf(s[n][r] - m_i[r]);
        pb[n][r] = pv;
        rs[r] += pv;
      }
#pragma unroll
    for (int off = 1; off < 16; off <<= 1)
#pragma unroll
      for (int r = 0; r < 4; ++r) rs[r] += __shfl_xor(rs[r], off);
#pragma unroll
    for (int r = 0; r < 4; ++r) l_i[r] = l_i[r] * fac[r] + rs[r];
#pragma unroll
    for (int dt = 0; dt < 4; ++dt)
#pragma unroll
      for (int r = 0; r < 4; ++r) acc_o[dt][r] *= fac[r];

    // P (C layout) -> LDS bf16, swizzled per row
#pragma unroll
    for (int n = 0; n < 4; ++n)
#pragma unroll
      for (int r = 0; r < 4; ++r) {
        int prow = ((l >> 4) << 2) + r;
        Psw[prow * 64 + ((n * 16 + fr) ^ ((prow & 7) << 3))] = f2bf(pb[n][r]);
      }
    asm volatile("s_waitcnt lgkmcnt(0)" ::: "memory");
    __builtin_amdgcn_sched_barrier(0);

    // PV: A = P[16q x 64k], B = V[64k x 64d] (Vs is d-major, rows = d)
    s16x8 pa0 = *(const s16x8*)(Psw + fr * 64 + (fg ^ fswz));
    s16x8 pa1 = *(const s16x8*)(Psw + fr * 64 + ((32 + fg) ^ fswz));
#pragma unroll
    for (int dt = 0; dt < 4; ++dt) {
      s16x8 bv0 = *(const s16x8*)(Vs + (dt * 16 + fr) * 64 + (fg ^ fswz));
      s16x8 bv1 = *(const s16x8*)(Vs + (dt * 16 + fr) * 64 + ((32 + fg) ^ fswz));
      acc_o[dt] = __builtin_amdgcn_mfma_f32_16x16x32_bf16(pa0, bv0, acc_o[dt], 0, 0, 0);
      acc_o[dt] = __builtin_amdgcn_mfma_f32_16x16x32_bf16(pa1, bv1, acc_o[dt], 0, 0, 0);
    }
  }

  float invl[4];
#pragma unroll
  for (int r = 0; r < 4; ++r) invl[r] = 1.f / l_i[r];
#pragma unroll
  for (int dt = 0; dt < 4; ++dt)
#pragma unroll
    for (int r = 0; r < 4; ++r) {
      size_t idx = (size_t)(b * 1024 + qrow_c + r) * 1024 + h * 64 + dt * 16 + fr;
      out[idx] = f2bf(acc_o[dt][r] * invl[r]);
    }
}

// ---------------- final depth-2 ----------------
__global__ __launch_bounds__(256) void depth2_kernel(
    const float* __restrict__ ffnout, const float* __restrict__ mixrest,
    const float* __restrict__ beta, float* __restrict__ Hout)
{
  const size_t stride = (size_t)gridDim.x * 256;
  const size_t n4 = (size_t)BB * LL * RR * DD / 4;
  for (size_t i = (size_t)blockIdx.x * 256 + threadIdx.x; i < n4; i += stride) {
    size_t e = i * 4;
    int d = (int)(e & 1023);
    int n = (int)((e >> 10) & 3);
    size_t bl = e >> 12;
    float be = beta[bl * 4 + n];
    float4 f = *(const float4*)&ffnout[bl * 1024 + d];
    float4 m = ((const float4*)mixrest)[i];
    float4 o;
    o.x = be * f.x + m.x; o.y = be * f.y + m.y;
    o.z = be * f.z + m.z; o.w = be * f.w + m.w;
    ((float4*)Hout)[i] = o;
  }
}

extern "C" void kernel_launch(void* const* d_in, const int* in_sizes, int n_in,
                              void* d_out, int out_size, void* d_ws, size_t ws_size,
                              hipStream_t stream) {
  const float* H       = (const float*)d_in[0];
  const float* hc1_nw  = (const float*)d_in[1];
  const float* hc1_afn = (const float*)d_in[2];
  const float* hc1_bfn = (const float*)d_in[3];
  const float* hc1_as  = (const float*)d_in[4];
  const float* hc1_bs  = (const float*)d_in[5];
  const float* hc1_sa  = (const float*)d_in[6];
  const float* hc1_sb  = (const float*)d_in[7];
  const float* attn_nw = (const float*)d_in[8];
  const float* qkv_w   = (const float*)d_in[9];
  const float* out_w   = (const float*)d_in[10];
  const float* hc2_nw  = (const float*)d_in[11];
  const float* hc2_afn = (const float*)d_in[12];
  const float* hc2_bfn = (const float*)d_in[13];
  const float* hc2_as  = (const float*)d_in[14];
  const float* hc2_bs  = (const float*)d_in[15];
  const float* hc2_sa  = (const float*)d_in[16];
  const float* hc2_sb  = (const float*)d_in[17];
  const float* ffn_nw  = (const float*)d_in[18];
  const float* fc1_w   = (const float*)d_in[19];
  const float* fc2_w   = (const float*)d_in[20];
  float* Hout = (float*)d_out;

  char* wsp = (char*)d_ws;
  size_t off = 0;
  auto carve = [&](size_t bytes) {
    void* p = wsp + off;
    off = (off + bytes + 255) & ~(size_t)255;
    return p;
  };
  u16* wq_bf   = (u16*)carve((size_t)3072 * 1024 * 2);
  u16* wo_bf   = (u16*)carve((size_t)1024 * 1024 * 2);
  u16* w1_bf   = (u16*)carve((size_t)4096 * 1024 * 2);
  u16* w2_bf   = (u16*)carve((size_t)4096 * 1024 * 2);
  u16* xbf     = (u16*)carve((size_t)4096 * 1024 * 2);
  float* mixrest = (float*)carve((size_t)4096 * 4096 * 4);
  float* beta1 = (float*)carve((size_t)16384 * 4);
  float* beta2 = (float*)carve((size_t)16384 * 4);
  // union region: {qk_bf 16MB + Vt 8MB} then reused as g1_bf 32MB
  char* uregion = (char*)carve((size_t)32 * 1024 * 1024);
  u16* qk_bf   = (u16*)uregion;
  u16* Vt      = (u16*)(uregion + (size_t)16 * 1024 * 1024);
  u16* g1_bf   = (u16*)uregion;
  u16* attn_bf = (u16*)carve((size_t)4096 * 1024 * 2);
  float* aof   = (float*)carve((size_t)4096 * 1024 * 4);

  // 1. weights -> bf16
  cvt_bf16_kernel<<<1024, 256, 0, stream>>>(qkv_w, wq_bf, 3072 * 1024 / 4);
  cvt_bf16_kernel<<<512, 256, 0, stream>>>(out_w, wo_bf, 1024 * 1024 / 4);
  cvt_bf16_kernel<<<1024, 256, 0, stream>>>(fc1_w, w1_bf, 4096 * 1024 / 4);
  cvt_bf16_kernel<<<1024, 256, 0, stream>>>(fc2_w, w2_bf, 4096 * 1024 / 4);
  // 2. width1 (+ pre-attn RMS)
  width_kernel<false><<<4096, 256, 0, stream>>>(H, nullptr, nullptr, nullptr,
      hc1_nw, hc1_afn, hc1_bfn, hc1_as, hc1_bs, hc1_sa, hc1_sb, attn_nw,
      mixrest, beta1, xbf);
  // 3. qkv -> bf16 Q,K + transposed V
  gemm_bt_kernel<2><<<32 * 24, 256, 0, stream>>>(xbf, wq_bf, nullptr, qk_bf, Vt, 4096, 3072, 1024);
  // 4. attention (MFMA flash)
  attn_mfma_kernel<<<dim3(16, 16, 4), 256, 0, stream>>>(qk_bf, Vt, attn_bf);
  // 5. out projection
  gemm_bt_kernel<0><<<32 * 8, 256, 0, stream>>>(attn_bf, wo_bf, aof, nullptr, nullptr, 4096, 1024, 1024);
  // 6. depth1 + width2 (+ pre-ffn RMS)
  width_kernel<true><<<4096, 256, 0, stream>>>(nullptr, mixrest, beta1, aof,
      hc2_nw, hc2_afn, hc2_bfn, hc2_as, hc2_bs, hc2_sa, hc2_sb, ffn_nw,
      mixrest, beta2, xbf);
  // 7. fc1 + gelu -> bf16
  gemm_bt_kernel<1><<<32 * 32, 256, 0, stream>>>(xbf, w1_bf, nullptr, g1_bf, nullptr, 4096, 4096, 1024);
  // 8. fc2
  gemm_bt_kernel<0><<<32 * 8, 256, 0, stream>>>(g1_bf, w2_bf, aof, nullptr, nullptr, 4096, 1024, 4096);
  // 9. depth2 -> output
  depth2_kernel<<<4096, 256, 0, stream>>>(aof, mixrest, beta2, Hout);
}

// Round 3
// 394.281 us; speedup vs baseline: 1.9998x; 1.1539x over previous
//
#include <hip/hip_runtime.h>
#include <math.h>

#define BB 4
#define LL 1024
#define RR 4
#define DD 1024
#define NHEADS 16
#define HDIM 64
#define FFD 4096
#define EPSV 1e-6f

typedef short s16x8 __attribute__((ext_vector_type(8)));
typedef float f32x4 __attribute__((ext_vector_type(4)));
typedef unsigned short u16;

__device__ inline unsigned short f2bf(float x) {
  unsigned u = __builtin_bit_cast(unsigned, x);
  unsigned r = (u + 0x7fffu + ((u >> 16) & 1u)) >> 16;
  return (unsigned short)r;
}

__device__ inline float wred_sum(float v) {
#pragma unroll
  for (int off = 32; off; off >>= 1) v += __shfl_down(v, off);
  return v;
}

__device__ inline void gload_lds16(const u16* g, u16* l) {
  __builtin_amdgcn_global_load_lds(
      (const __attribute__((address_space(1))) unsigned int*)g,
      (__attribute__((address_space(3))) unsigned int*)l, 16, 0, 0);
}

// ---------------- fused f32 -> bf16 for the 4 weight tensors ----------------
__global__ __launch_bounds__(256) void cvt4_kernel(
    const float* __restrict__ s0, const float* __restrict__ s1,
    const float* __restrict__ s2, const float* __restrict__ s3,
    u16* __restrict__ d0, u16* __restrict__ d1,
    u16* __restrict__ d2, u16* __restrict__ d3) {
  const int n0 = 786432, n1 = 262144, n2 = 1048576, n3 = 1048576;  // float4 counts
  const int total = n0 + n1 + n2 + n3;
  for (int i = blockIdx.x * 256 + threadIdx.x; i < total; i += gridDim.x * 256) {
    const float4* src; ushort4* dst; int j;
    if (i < n0)                { src = (const float4*)s0; dst = (ushort4*)d0; j = i; }
    else if (i < n0 + n1)      { src = (const float4*)s1; dst = (ushort4*)d1; j = i - n0; }
    else if (i < n0 + n1 + n2) { src = (const float4*)s2; dst = (ushort4*)d2; j = i - n0 - n1; }
    else                       { src = (const float4*)s3; dst = (ushort4*)d3; j = i - n0 - n1 - n2; }
    float4 v = src[j];
    ushort4 o;
    o.x = f2bf(v.x); o.y = f2bf(v.y); o.z = f2bf(v.z); o.w = f2bf(v.w);
    dst[j] = o;
  }
}

// ---------------- width (hyper-connection) kernel ----------------
template<bool FUSED>
__global__ __launch_bounds__(256) void width_kernel(
    const float* __restrict__ Hin,
    const float* mixrest_in,
    const float* __restrict__ beta_in,
    const float* __restrict__ attnout,     // partial 0
    const float* __restrict__ attnout2,    // partial 1 (FUSED only)
    const float* __restrict__ hc_norm_w,
    const float* __restrict__ alpha_fn,
    const float* __restrict__ beta_fn,
    const float* __restrict__ a_scale,
    const float* __restrict__ b_scale,
    const float* __restrict__ s_alpha,
    const float* __restrict__ s_beta,
    const float* __restrict__ post_norm_w,
    float* mixrest_out,
    float* __restrict__ beta_out,
    u16* __restrict__ x_out)
{
  const int bl = blockIdx.x;
  const int t = threadIdx.x;
  const int wid = t >> 6;
  __shared__ __align__(16) float Hs[4 * 1024];
  __shared__ __align__(16) float m0[1024];
  __shared__ float scr[96];
  __shared__ float alpha_s[4][5];
  __shared__ float beta_s[4];
  __shared__ float inv_s[4];
  __shared__ float inv0_s;

  if (FUSED) {
    float4 a0 = ((const float4*)(attnout + (size_t)bl * 1024))[t];
    float4 a1 = ((const float4*)(attnout2 + (size_t)bl * 1024))[t];
    float4 s; s.x = a0.x + a1.x; s.y = a0.y + a1.y; s.z = a0.z + a1.z; s.w = a0.w + a1.w;
    ((float4*)m0)[t] = s;
    __syncthreads();
    for (int i = t; i < 1024; i += 256) {
      int n = i >> 8;
      float be = beta_in[bl * 4 + n];
      float4 mr = ((const float4*)(mixrest_in + (size_t)bl * 4096))[i];
      float4 ao = ((const float4*)m0)[i & 255];
      float4 hv;
      hv.x = be * ao.x + mr.x; hv.y = be * ao.y + mr.y;
      hv.z = be * ao.z + mr.z; hv.w = be * ao.w + mr.w;
      ((float4*)Hs)[i] = hv;
    }
  } else {
    for (int i = t; i < 1024; i += 256)
      ((float4*)Hs)[i] = ((const float4*)(Hin + (size_t)bl * 4096))[i];
  }
  __syncthreads();

  float ss[4];
#pragma unroll
  for (int n = 0; n < 4; ++n) {
    float a = 0.f;
    for (int d = t; d < 1024; d += 256) { float v = Hs[n * 1024 + d]; a += v * v; }
    ss[n] = a;
  }
#pragma unroll
  for (int n = 0; n < 4; ++n) {
    float r = wred_sum(ss[n]);
    if ((t & 63) == 0) scr[wid * 4 + n] = r;
  }
  __syncthreads();
  if (t < 4) {
    float tot = scr[t] + scr[4 + t] + scr[8 + t] + scr[12 + t];
    inv_s[t] = 1.f / (sqrtf(tot * (1.f / 1024.f)) + EPSV);
  }
  __syncthreads();
  float inv[4] = {inv_s[0], inv_s[1], inv_s[2], inv_s[3]};

  float dots[4][6];
#pragma unroll
  for (int n = 0; n < 4; ++n)
#pragma unroll
    for (int k = 0; k < 6; ++k) dots[n][k] = 0.f;
  for (int d = t; d < 1024; d += 256) {
    float w = hc_norm_w[d];
    float a0 = alpha_fn[d * 5 + 0], a1 = alpha_fn[d * 5 + 1], a2 = alpha_fn[d * 5 + 2],
          a3 = alpha_fn[d * 5 + 3], a4 = alpha_fn[d * 5 + 4];
    float bfv = beta_fn[d];
#pragma unroll
    for (int n = 0; n < 4; ++n) {
      float nh = Hs[n * 1024 + d] * w * inv[n];
      dots[n][0] += nh * a0; dots[n][1] += nh * a1; dots[n][2] += nh * a2;
      dots[n][3] += nh * a3; dots[n][4] += nh * a4; dots[n][5] += nh * bfv;
    }
  }
  __syncthreads();
#pragma unroll
  for (int n = 0; n < 4; ++n)
#pragma unroll
    for (int k = 0; k < 6; ++k) {
      float r = wred_sum(dots[n][k]);
      if ((t & 63) == 0) scr[wid * 24 + n * 6 + k] = r;
    }
  __syncthreads();
  if (t < 24) {
    float raw = scr[t] + scr[24 + t] + scr[48 + t] + scr[72 + t];
    int n = t / 6, k = t % 6;
    if (k < 5) alpha_s[n][k] = tanhf(raw) * a_scale[0] + s_alpha[n * 5 + k];
    else       beta_s[n]     = tanhf(raw) * b_scale[0] + s_beta[n];
  }
  __syncthreads();

  {
    int i = t;
    float4 h0 = ((const float4*)Hs)[i];
    float4 h1 = ((const float4*)Hs)[256 + i];
    float4 h2 = ((const float4*)Hs)[512 + i];
    float4 h3 = ((const float4*)Hs)[768 + i];
#pragma unroll
    for (int k = 0; k < 5; ++k) {
      float c0 = alpha_s[0][k], c1 = alpha_s[1][k], c2 = alpha_s[2][k], c3 = alpha_s[3][k];
      float4 mv;
      mv.x = c0 * h0.x + c1 * h1.x + c2 * h2.x + c3 * h3.x;
      mv.y = c0 * h0.y + c1 * h1.y + c2 * h2.y + c3 * h3.y;
      mv.z = c0 * h0.z + c1 * h1.z + c2 * h2.z + c3 * h3.z;
      mv.w = c0 * h0.w + c1 * h1.w + c2 * h2.w + c3 * h3.w;
      if (k == 0) ((float4*)m0)[i] = mv;
      else ((float4*)(mixrest_out + (size_t)bl * 4096 + (size_t)(k - 1) * 1024))[i] = mv;
    }
  }
  if (t < 4) beta_out[bl * 4 + t] = beta_s[t];
  __syncthreads();

  {
    float a = 0.f;
    for (int d = t; d < 1024; d += 256) { float v = m0[d]; a += v * v; }
    float r = wred_sum(a);
    if ((t & 63) == 0) scr[wid] = r;
  }
  __syncthreads();
  if (t == 0) {
    float tot = scr[0] + scr[1] + scr[2] + scr[3];
    inv0_s = 1.f / (sqrtf(tot * (1.f / 1024.f)) + EPSV);
  }
  __syncthreads();
  {
    float iv = inv0_s;
    float4 mv = ((const float4*)m0)[t];
    float4 wv = ((const float4*)post_norm_w)[t];
    ushort4 ov;
    ov.x = f2bf(wv.x * mv.x * iv);
    ov.y = f2bf(wv.y * mv.y * iv);
    ov.z = f2bf(wv.z * mv.z * iv);
    ov.w = f2bf(wv.w * mv.w * iv);
    ((ushort4*)(x_out + (size_t)bl * 1024))[t] = ov;
  }
}

// ---------------- bf16 GEMM: C[M,N] = A[M,K] @ W[N,K]^T ----------------
// double-buffered prefetch K-loop; optional split-K (SPLIT>1 -> f32 partials).
// EPI=0: f32 out; EPI=1: gelu->bf16; EPI=2: qkv split (Q,K bf16 [M,2048], V transposed)
template<int EPI, int SPLIT>
__global__ __launch_bounds__(256) void gemm_bt_kernel(
    const u16* __restrict__ A, const u16* __restrict__ W,
    float* __restrict__ Cf, u16* __restrict__ Cb, u16* __restrict__ Vt,
    int M, int N, int K)
{
  __shared__ __align__(16) u16 As[2][128 * 32];
  __shared__ __align__(16) u16 Bs[2][128 * 32];
  const int tn = N >> 7, tm = M >> 7;
  int bid = blockIdx.x;
  const int nwg = gridDim.x;
  if ((nwg & 7) == 0) bid = (bid & 7) * (nwg >> 3) + (bid >> 3);  // XCD swizzle
  const int ts = tm * tn;
  const int sK = bid / ts;
  const int tb = bid - sK * ts;
  const int bm = tb / tn, bn = tb % tn;
  const int Kc = K / SPLIT;
  const int kbeg = sK * Kc;

  const int t = threadIdx.x, l = t & 63, w = t >> 6;
  const int wr = w >> 1, wc = w & 1;
  const int m0 = bm << 7, n0 = bn << 7;
  const int ssc = (((l & 3) ^ ((l >> 2) & 3)) << 3);
  const int srA = m0 + (w << 5) + (l >> 2);
  const int srB = n0 + (w << 5) + (l >> 2);
  const int ldso = (w << 10);
  const int fr = l & 15;
  const int fc8 = (((l >> 4) ^ (l & 3)) << 3);

  f32x4 acc[4][4];
#pragma unroll
  for (int i = 0; i < 4; ++i)
#pragma unroll
    for (int j = 0; j < 4; ++j)
#pragma unroll
      for (int e = 0; e < 4; ++e) acc[i][j][e] = 0.f;

  const u16* pa0 = A + (size_t)srA * K + kbeg + ssc;
  const u16* pa1 = A + (size_t)(srA + 16) * K + kbeg + ssc;
  const u16* pb0 = W + (size_t)srB * K + kbeg + ssc;
  const u16* pb1 = W + (size_t)(srB + 16) * K + kbeg + ssc;

#define STAGE(buf, koff)                              \
  do {                                                \
    gload_lds16(pa0 + (koff), &As[buf][ldso]);        \
    gload_lds16(pa1 + (koff), &As[buf][ldso + 512]);  \
    gload_lds16(pb0 + (koff), &Bs[buf][ldso]);        \
    gload_lds16(pb1 + (koff), &Bs[buf][ldso + 512]);  \
  } while (0)

  STAGE(0, 0);
  __syncthreads();
  const int nt = Kc >> 5;
  int cur = 0;
  for (int kt = 0; kt < nt; ++kt) {
    if (kt + 1 < nt) STAGE(cur ^ 1, (kt + 1) << 5);
    s16x8 af[4], bfr[4];
#pragma unroll
    for (int m = 0; m < 4; ++m)
      af[m] = *(const s16x8*)(&As[cur][(wr * 64 + m * 16 + fr) * 32 + fc8]);
#pragma unroll
    for (int n = 0; n < 4; ++n)
      bfr[n] = *(const s16x8*)(&Bs[cur][(wc * 64 + n * 16 + fr) * 32 + fc8]);
#pragma unroll
    for (int m = 0; m < 4; ++m)
#pragma unroll
      for (int n = 0; n < 4; ++n)
        acc[m][n] = __builtin_amdgcn_mfma_f32_16x16x32_bf16(af[m], bfr[n], acc[m][n], 0, 0, 0);
    __syncthreads();
    cur ^= 1;
  }
#undef STAGE

  const int rb = m0 + wr * 64 + ((l >> 4) << 2);
  const int cb = n0 + wc * 64 + fr;
  if (SPLIT > 1) {
    float* Cp = Cf + (size_t)sK * M * N;
#pragma unroll
    for (int m = 0; m < 4; ++m)
#pragma unroll
      for (int n = 0; n < 4; ++n)
#pragma unroll
        for (int j = 0; j < 4; ++j)
          Cp[(size_t)(rb + m * 16 + j) * N + cb + n * 16] = acc[m][n][j];
  } else {
#pragma unroll
    for (int m = 0; m < 4; ++m)
#pragma unroll
      for (int n = 0; n < 4; ++n) {
        if (EPI == 2 && n0 >= 2048) {
          int cc = cb + n * 16 - 2048;
          int hh = cc >> 6, dd = cc & 63;
          int r0 = rb + m * 16;
          ushort4 ov;
          ov.x = f2bf(acc[m][n][0]); ov.y = f2bf(acc[m][n][1]);
          ov.z = f2bf(acc[m][n][2]); ov.w = f2bf(acc[m][n][3]);
          *(ushort4*)&Vt[((size_t)((r0 >> 10) * 16 + hh) * 64 + dd) * 1024 + (r0 & 1023)] = ov;
        } else {
#pragma unroll
          for (int j = 0; j < 4; ++j) {
            int r = rb + m * 16 + j;
            int c = cb + n * 16;
            float v = acc[m][n][j];
            if (EPI == 1) {
              v = 0.5f * v * (1.f + erff(v * 0.70710678118f));
              Cb[(size_t)r * N + c] = f2bf(v);
            } else if (EPI == 2) {
              Cb[(size_t)r * 2048 + c] = f2bf(v);
            } else {
              Cf[(size_t)r * N + c] = v;
            }
          }
        }
      }
  }
}

// ---------------- MFMA flash attention, causal ----------------
__global__ __launch_bounds__(256) void attn_mfma_kernel(
    const u16* __restrict__ qk, const u16* __restrict__ Vt, u16* __restrict__ out)
{
  const int h = blockIdx.y, b = blockIdx.z;
  const int qt = (h & 1) ? (15 - blockIdx.x) : blockIdx.x;
  const int t = threadIdx.x, l = t & 63, w = t >> 6;
  const int q0 = qt << 6;
  __shared__ __align__(16) u16 Ks[64 * 64];
  __shared__ __align__(16) u16 Vs[64 * 64];
  __shared__ __align__(16) u16 Ps[4][16 * 64];

  const int fr = l & 15;
  const int fg = (l >> 4) << 3;
  const int fswz = (fr & 7) << 3;

  const int qrow = q0 + w * 16 + fr;
  const size_t qbase = (size_t)(b * 1024 + qrow) * 2048 + h * 64 + fg;
  const s16x8 aq0 = *(const s16x8*)(qk + qbase);
  const s16x8 aq1 = *(const s16x8*)(qk + qbase + 32);

  f32x4 acc_o[4];
#pragma unroll
  for (int i = 0; i < 4; ++i)
#pragma unroll
    for (int e = 0; e < 4; ++e) acc_o[i][e] = 0.f;
  float m_i[4] = {-INFINITY, -INFINITY, -INFINITY, -INFINITY};
  float l_i[4] = {0.f, 0.f, 0.f, 0.f};

  const int srow = t >> 2;
  const int sc = (t & 3) << 4;
  const int c0s = sc ^ ((srow & 7) << 3);
  const int c1s = (sc + 8) ^ ((srow & 7) << 3);
  const int qrow_c = q0 + w * 16 + ((l >> 4) << 2);
  u16* Psw = &Ps[w][0];
  const int nkt = qt + 1;

  for (int kt = 0; kt < nkt; ++kt) {
    const int kb = kt << 6;
    __syncthreads();
    {
      size_t kg = (size_t)(b * 1024 + kb + srow) * 2048 + 1024 + h * 64 + sc;
      s16x8 kv0 = *(const s16x8*)(qk + kg);
      s16x8 kv1 = *(const s16x8*)(qk + kg + 8);
      size_t vg = (size_t)((b * 16 + h) * 64 + srow) * 1024 + kb + sc;
      s16x8 vv0 = *(const s16x8*)(Vt + vg);
      s16x8 vv1 = *(const s16x8*)(Vt + vg + 8);
      *(s16x8*)(Ks + srow * 64 + c0s) = kv0;
      *(s16x8*)(Ks + srow * 64 + c1s) = kv1;
      *(s16x8*)(Vs + srow * 64 + c0s) = vv0;
      *(s16x8*)(Vs + srow * 64 + c1s) = vv1;
    }
    __syncthreads();

    f32x4 s[4];
#pragma unroll
    for (int n = 0; n < 4; ++n) {
#pragma unroll
      for (int e = 0; e < 4; ++e) s[n][e] = 0.f;
      s16x8 bk0 = *(const s16x8*)(Ks + (n * 16 + fr) * 64 + (fg ^ fswz));
      s16x8 bk1 = *(const s16x8*)(Ks + (n * 16 + fr) * 64 + ((32 + fg) ^ fswz));
      s[n] = __builtin_amdgcn_mfma_f32_16x16x32_bf16(aq0, bk0, s[n], 0, 0, 0);
      s[n] = __builtin_amdgcn_mfma_f32_16x16x32_bf16(aq1, bk1, s[n], 0, 0, 0);
    }
#pragma unroll
    for (int n = 0; n < 4; ++n)
#pragma unroll
      for (int e = 0; e < 4; ++e) s[n][e] *= 0.125f;
    if (kt == qt) {
#pragma unroll
      for (int n = 0; n < 4; ++n) {
        int kc = kb + n * 16 + fr;
#pragma unroll
        for (int r = 0; r < 4; ++r)
          if (kc > qrow_c + r) s[n][r] = -INFINITY;
      }
    }

    float rm[4], fac[4];
#pragma unroll
    for (int r = 0; r < 4; ++r)
      rm[r] = fmaxf(fmaxf(s[0][r], s[1][r]), fmaxf(s[2][r], s[3][r]));
#pragma unroll
    for (int off = 1; off < 16; off <<= 1)
#pragma unroll
      for (int r = 0; r < 4; ++r) rm[r] = fmaxf(rm[r], __shfl_xor(rm[r], off));
#pragma unroll
    for (int r = 0; r < 4; ++r) {
      float mn = fmaxf(m_i[r], rm[r]);
      fac[r] = __expf(m_i[r] - mn);
      m_i[r] = mn;
    }
    float rs[4] = {0.f, 0.f, 0.f, 0.f};
    float pb[4][4];
#pragma unroll
    for (int n = 0; n < 4; ++n)
#pragma unroll
      for (int r = 0; r < 4; ++r) {
        float pv = __expf(s[n][r] - m_i[r]);
        pb[n][r] = pv;
        rs[r] += pv;
      }
#pragma unroll
    for (int off = 1; off < 16; off <<= 1)
#pragma unroll
      for (int r = 0; r < 4; ++r) rs[r] += __shfl_xor(rs[r], off);
#pragma unroll
    for (int r = 0; r < 4; ++r) l_i[r] = l_i[r] * fac[r] + rs[r];
#pragma unroll
    for (int dt = 0; dt < 4; ++dt)
#pragma unroll
      for (int r = 0; r < 4; ++r) acc_o[dt][r] *= fac[r];

#pragma unroll
    for (int n = 0; n < 4; ++n)
#pragma unroll
      for (int r = 0; r < 4; ++r) {
        int prow = ((l >> 4) << 2) + r;
        Psw[prow * 64 + ((n * 16 + fr) ^ ((prow & 7) << 3))] = f2bf(pb[n][r]);
      }
    asm volatile("s_waitcnt lgkmcnt(0)" ::: "memory");
    __builtin_amdgcn_sched_barrier(0);

    s16x8 pa0 = *(const s16x8*)(Psw + fr * 64 + (fg ^ fswz));
    s16x8 pa1 = *(const s16x8*)(Psw + fr * 64 + ((32 + fg) ^ fswz));
#pragma unroll
    for (int dt = 0; dt < 4; ++dt) {
      s16x8 bv0 = *(const s16x8*)(Vs + (dt * 16 + fr) * 64 + (fg ^ fswz));
      s16x8 bv1 = *(const s16x8*)(Vs + (dt * 16 + fr) * 64 + ((32 + fg) ^ fswz));
      acc_o[dt] = __builtin_amdgcn_mfma_f32_16x16x32_bf16(pa0, bv0, acc_o[dt], 0, 0, 0);
      acc_o[dt] = __builtin_amdgcn_mfma_f32_16x16x32_bf16(pa1, bv1, acc_o[dt], 0, 0, 0);
    }
  }

  float invl[4];
#pragma unroll
  for (int r = 0; r < 4; ++r) invl[r] = 1.f / l_i[r];
#pragma unroll
  for (int dt = 0; dt < 4; ++dt)
#pragma unroll
    for (int r = 0; r < 4; ++r) {
      size_t idx = (size_t)(b * 1024 + qrow_c + r) * 1024 + h * 64 + dt * 16 + fr;
      out[idx] = f2bf(acc_o[dt][r] * invl[r]);
    }
}

// ---------------- final depth-2 (sums 2 fc2 partials) ----------------
__global__ __launch_bounds__(256) void depth2_kernel(
    const float* __restrict__ p0, const float* __restrict__ p1,
    const float* __restrict__ mixrest,
    const float* __restrict__ beta, float* __restrict__ Hout)
{
  const size_t stride = (size_t)gridDim.x * 256;
  const size_t n4 = (size_t)BB * LL * RR * DD / 4;
  for (size_t i = (size_t)blockIdx.x * 256 + threadIdx.x; i < n4; i += stride) {
    size_t e = i * 4;
    int d = (int)(e & 1023);
    int n = (int)((e >> 10) & 3);
    size_t bl = e >> 12;
    float be = beta[bl * 4 + n];
    float4 f0 = *(const float4*)&p0[bl * 1024 + d];
    float4 f1 = *(const float4*)&p1[bl * 1024 + d];
    float4 m = ((const float4*)mixrest)[i];
    float4 o;
    o.x = be * (f0.x + f1.x) + m.x; o.y = be * (f0.y + f1.y) + m.y;
    o.z = be * (f0.z + f1.z) + m.z; o.w = be * (f0.w + f1.w) + m.w;
    ((float4*)Hout)[i] = o;
  }
}

extern "C" void kernel_launch(void* const* d_in, const int* in_sizes, int n_in,
                              void* d_out, int out_size, void* d_ws, size_t ws_size,
                              hipStream_t stream) {
  const float* H       = (const float*)d_in[0];
  const float* hc1_nw  = (const float*)d_in[1];
  const float* hc1_afn = (const float*)d_in[2];
  const float* hc1_bfn = (const float*)d_in[3];
  const float* hc1_as  = (const float*)d_in[4];
  const float* hc1_bs  = (const float*)d_in[5];
  const float* hc1_sa  = (const float*)d_in[6];
  const float* hc1_sb  = (const float*)d_in[7];
  const float* attn_nw = (const float*)d_in[8];
  const float* qkv_w   = (const float*)d_in[9];
  const float* out_w   = (const float*)d_in[10];
  const float* hc2_nw  = (const float*)d_in[11];
  const float* hc2_afn = (const float*)d_in[12];
  const float* hc2_bfn = (const float*)d_in[13];
  const float* hc2_as  = (const float*)d_in[14];
  const float* hc2_bs  = (const float*)d_in[15];
  const float* hc2_sa  = (const float*)d_in[16];
  const float* hc2_sb  = (const float*)d_in[17];
  const float* ffn_nw  = (const float*)d_in[18];
  const float* fc1_w   = (const float*)d_in[19];
  const float* fc2_w   = (const float*)d_in[20];
  float* Hout = (float*)d_out;

  char* wsp = (char*)d_ws;
  size_t off = 0;
  auto carve = [&](size_t bytes) {
    void* p = wsp + off;
    off = (off + bytes + 255) & ~(size_t)255;
    return p;
  };
  u16* wq_bf   = (u16*)carve((size_t)3072 * 1024 * 2);
  u16* wo_bf   = (u16*)carve((size_t)1024 * 1024 * 2);
  u16* w1_bf   = (u16*)carve((size_t)4096 * 1024 * 2);
  u16* w2_bf   = (u16*)carve((size_t)4096 * 1024 * 2);
  u16* xbf     = (u16*)carve((size_t)4096 * 1024 * 2);
  float* mixrest = (float*)carve((size_t)4096 * 4096 * 4);
  float* beta1 = (float*)carve((size_t)16384 * 4);
  float* beta2 = (float*)carve((size_t)16384 * 4);
  char* uregion = (char*)carve((size_t)32 * 1024 * 1024);
  u16* qk_bf   = (u16*)uregion;
  u16* Vt      = (u16*)(uregion + (size_t)16 * 1024 * 1024);
  u16* g1_bf   = (u16*)uregion;
  u16* attn_bf = (u16*)carve((size_t)4096 * 1024 * 2);
  float* parts = (float*)carve((size_t)2 * 4096 * 1024 * 4);  // 2 f32 partials
  float* part1 = parts + (size_t)4096 * 1024;

  // 1. weights -> bf16 (fused)
  cvt4_kernel<<<2048, 256, 0, stream>>>(qkv_w, out_w, fc1_w, fc2_w, wq_bf, wo_bf, w1_bf, w2_bf);
  // 2. width1 (+ pre-attn RMS)
  width_kernel<false><<<4096, 256, 0, stream>>>(H, nullptr, nullptr, nullptr, nullptr,
      hc1_nw, hc1_afn, hc1_bfn, hc1_as, hc1_bs, hc1_sa, hc1_sb, attn_nw,
      mixrest, beta1, xbf);
  // 3. qkv -> bf16 Q,K + transposed V
  gemm_bt_kernel<2, 1><<<32 * 24, 256, 0, stream>>>(xbf, wq_bf, nullptr, qk_bf, Vt, 4096, 3072, 1024);
  // 4. attention (MFMA flash)
  attn_mfma_kernel<<<dim3(16, 16, 4), 256, 0, stream>>>(qk_bf, Vt, attn_bf);
  // 5. out projection, split-K=2 -> f32 partials
  gemm_bt_kernel<0, 2><<<32 * 8 * 2, 256, 0, stream>>>(attn_bf, wo_bf, parts, nullptr, nullptr, 4096, 1024, 1024);
  // 6. depth1 + width2 (+ pre-ffn RMS)
  width_kernel<true><<<4096, 256, 0, stream>>>(nullptr, mixrest, beta1, parts, part1,
      hc2_nw, hc2_afn, hc2_bfn, hc2_as, hc2_bs, hc2_sa, hc2_sb, ffn_nw,
      mixrest, beta2, xbf);
  // 7. fc1 + gelu -> bf16
  gemm_bt_kernel<1, 1><<<32 * 32, 256, 0, stream>>>(xbf, w1_bf, nullptr, g1_bf, nullptr, 4096, 4096, 1024);
  // 8. fc2, split-K=2 -> f32 partials
  gemm_bt_kernel<0, 2><<<32 * 8 * 2, 256, 0, stream>>>(g1_bf, w2_bf, parts, nullptr, nullptr, 4096, 1024, 4096);
  // 9. depth2 -> output
  depth2_kernel<<<4096, 256, 0, stream>>>(parts, part1, mixrest, beta2, Hout);
}

// Round 4
// 393.239 us; speedup vs baseline: 2.0051x; 1.0026x over previous
//
#include <hip/hip_runtime.h>
#include <math.h>

#define BB 4
#define LL 1024
#define RR 4
#define DD 1024
#define NHEADS 16
#define HDIM 64
#define FFD 4096
#define EPSV 1e-6f

typedef short s16x8 __attribute__((ext_vector_type(8)));
typedef float f32x4 __attribute__((ext_vector_type(4)));
typedef unsigned short u16;

__device__ inline unsigned short f2bf(float x) {
  unsigned u = __builtin_bit_cast(unsigned, x);
  unsigned r = (u + 0x7fffu + ((u >> 16) & 1u)) >> 16;
  return (unsigned short)r;
}

__device__ inline float wred_sum(float v) {
#pragma unroll
  for (int off = 32; off; off >>= 1) v += __shfl_down(v, off);
  return v;
}

__device__ inline void gload_lds16(const u16* g, u16* l) {
  __builtin_amdgcn_global_load_lds(
      (const __attribute__((address_space(1))) unsigned int*)g,
      (__attribute__((address_space(3))) unsigned int*)l, 16, 0, 0);
}

// ---------------- fused f32 -> bf16 for the 4 weight tensors ----------------
__global__ __launch_bounds__(256) void cvt4_kernel(
    const float* __restrict__ s0, const float* __restrict__ s1,
    const float* __restrict__ s2, const float* __restrict__ s3,
    u16* __restrict__ d0, u16* __restrict__ d1,
    u16* __restrict__ d2, u16* __restrict__ d3) {
  const int n0 = 786432, n1 = 262144, n2 = 1048576, n3 = 1048576;  // float4 counts
  const int total = n0 + n1 + n2 + n3;
  for (int i = blockIdx.x * 256 + threadIdx.x; i < total; i += gridDim.x * 256) {
    const float4* src; ushort4* dst; int j;
    if (i < n0)                { src = (const float4*)s0; dst = (ushort4*)d0; j = i; }
    else if (i < n0 + n1)      { src = (const float4*)s1; dst = (ushort4*)d1; j = i - n0; }
    else if (i < n0 + n1 + n2) { src = (const float4*)s2; dst = (ushort4*)d2; j = i - n0 - n1; }
    else                       { src = (const float4*)s3; dst = (ushort4*)d3; j = i - n0 - n1 - n2; }
    float4 v = src[j];
    ushort4 o;
    o.x = f2bf(v.x); o.y = f2bf(v.y); o.z = f2bf(v.z); o.w = f2bf(v.w);
    dst[j] = o;
  }
}

// ---------------- width (hyper-connection) kernel ----------------
template<bool FUSED>
__global__ __launch_bounds__(256) void width_kernel(
    const float* __restrict__ Hin,
    const float* mixrest_in,
    const float* __restrict__ beta_in,
    const float* __restrict__ attnout,     // partial 0
    const float* __restrict__ attnout2,    // partial 1 (FUSED only)
    const float* __restrict__ hc_norm_w,
    const float* __restrict__ alpha_fn,
    const float* __restrict__ beta_fn,
    const float* __restrict__ a_scale,
    const float* __restrict__ b_scale,
    const float* __restrict__ s_alpha,
    const float* __restrict__ s_beta,
    const float* __restrict__ post_norm_w,
    float* mixrest_out,
    float* __restrict__ beta_out,
    u16* __restrict__ x_out)
{
  const int bl = blockIdx.x;
  const int t = threadIdx.x;
  const int wid = t >> 6;
  __shared__ __align__(16) float Hs[4 * 1024];
  __shared__ __align__(16) float m0[1024];
  __shared__ float scr[96];
  __shared__ float alpha_s[4][5];
  __shared__ float beta_s[4];
  __shared__ float inv_s[4];
  __shared__ float inv0_s;

  if (FUSED) {
    float4 a0 = ((const float4*)(attnout + (size_t)bl * 1024))[t];
    float4 a1 = ((const float4*)(attnout2 + (size_t)bl * 1024))[t];
    float4 s; s.x = a0.x + a1.x; s.y = a0.y + a1.y; s.z = a0.z + a1.z; s.w = a0.w + a1.w;
    ((float4*)m0)[t] = s;
    __syncthreads();
    for (int i = t; i < 1024; i += 256) {
      int n = i >> 8;
      float be = beta_in[bl * 4 + n];
      float4 mr = ((const float4*)(mixrest_in + (size_t)bl * 4096))[i];
      float4 ao = ((const float4*)m0)[i & 255];
      float4 hv;
      hv.x = be * ao.x + mr.x; hv.y = be * ao.y + mr.y;
      hv.z = be * ao.z + mr.z; hv.w = be * ao.w + mr.w;
      ((float4*)Hs)[i] = hv;
    }
  } else {
    for (int i = t; i < 1024; i += 256)
      ((float4*)Hs)[i] = ((const float4*)(Hin + (size_t)bl * 4096))[i];
  }
  __syncthreads();

  float ss[4];
#pragma unroll
  for (int n = 0; n < 4; ++n) {
    float a = 0.f;
    for (int d = t; d < 1024; d += 256) { float v = Hs[n * 1024 + d]; a += v * v; }
    ss[n] = a;
  }
#pragma unroll
  for (int n = 0; n < 4; ++n) {
    float r = wred_sum(ss[n]);
    if ((t & 63) == 0) scr[wid * 4 + n] = r;
  }
  __syncthreads();
  if (t < 4) {
    float tot = scr[t] + scr[4 + t] + scr[8 + t] + scr[12 + t];
    inv_s[t] = 1.f / (sqrtf(tot * (1.f / 1024.f)) + EPSV);
  }
  __syncthreads();
  float inv[4] = {inv_s[0], inv_s[1], inv_s[2], inv_s[3]};

  float dots[4][6];
#pragma unroll
  for (int n = 0; n < 4; ++n)
#pragma unroll
    for (int k = 0; k < 6; ++k) dots[n][k] = 0.f;
  for (int d = t; d < 1024; d += 256) {
    float w = hc_norm_w[d];
    float a0 = alpha_fn[d * 5 + 0], a1 = alpha_fn[d * 5 + 1], a2 = alpha_fn[d * 5 + 2],
          a3 = alpha_fn[d * 5 + 3], a4 = alpha_fn[d * 5 + 4];
    float bfv = beta_fn[d];
#pragma unroll
    for (int n = 0; n < 4; ++n) {
      float nh = Hs[n * 1024 + d] * w * inv[n];
      dots[n][0] += nh * a0; dots[n][1] += nh * a1; dots[n][2] += nh * a2;
      dots[n][3] += nh * a3; dots[n][4] += nh * a4; dots[n][5] += nh * bfv;
    }
  }
  __syncthreads();
#pragma unroll
  for (int n = 0; n < 4; ++n)
#pragma unroll
    for (int k = 0; k < 6; ++k) {
      float r = wred_sum(dots[n][k]);
      if ((t & 63) == 0) scr[wid * 24 + n * 6 + k] = r;
    }
  __syncthreads();
  if (t < 24) {
    float raw = scr[t] + scr[24 + t] + scr[48 + t] + scr[72 + t];
    int n = t / 6, k = t % 6;
    if (k < 5) alpha_s[n][k] = tanhf(raw) * a_scale[0] + s_alpha[n * 5 + k];
    else       beta_s[n]     = tanhf(raw) * b_scale[0] + s_beta[n];
  }
  __syncthreads();

  {
    int i = t;
    float4 h0 = ((const float4*)Hs)[i];
    float4 h1 = ((const float4*)Hs)[256 + i];
    float4 h2 = ((const float4*)Hs)[512 + i];
    float4 h3 = ((const float4*)Hs)[768 + i];
#pragma unroll
    for (int k = 0; k < 5; ++k) {
      float c0 = alpha_s[0][k], c1 = alpha_s[1][k], c2 = alpha_s[2][k], c3 = alpha_s[3][k];
      float4 mv;
      mv.x = c0 * h0.x + c1 * h1.x + c2 * h2.x + c3 * h3.x;
      mv.y = c0 * h0.y + c1 * h1.y + c2 * h2.y + c3 * h3.y;
      mv.z = c0 * h0.z + c1 * h1.z + c2 * h2.z + c3 * h3.z;
      mv.w = c0 * h0.w + c1 * h1.w + c2 * h2.w + c3 * h3.w;
      if (k == 0) ((float4*)m0)[i] = mv;
      else ((float4*)(mixrest_out + (size_t)bl * 4096 + (size_t)(k - 1) * 1024))[i] = mv;
    }
  }
  if (t < 4) beta_out[bl * 4 + t] = beta_s[t];
  __syncthreads();

  {
    float a = 0.f;
    for (int d = t; d < 1024; d += 256) { float v = m0[d]; a += v * v; }
    float r = wred_sum(a);
    if ((t & 63) == 0) scr[wid] = r;
  }
  __syncthreads();
  if (t == 0) {
    float tot = scr[0] + scr[1] + scr[2] + scr[3];
    inv0_s = 1.f / (sqrtf(tot * (1.f / 1024.f)) + EPSV);
  }
  __syncthreads();
  {
    float iv = inv0_s;
    float4 mv = ((const float4*)m0)[t];
    float4 wv = ((const float4*)post_norm_w)[t];
    ushort4 ov;
    ov.x = f2bf(wv.x * mv.x * iv);
    ov.y = f2bf(wv.y * mv.y * iv);
    ov.z = f2bf(wv.z * mv.z * iv);
    ov.w = f2bf(wv.w * mv.w * iv);
    ((ushort4*)(x_out + (size_t)bl * 1024))[t] = ov;
  }
}

// ---------------- bf16 GEMM: C[M,N] = A[M,K] @ W[N,K]^T ----------------
// 3-buffer depth-2 prefetch with counted vmcnt (T4); raw s_barrier (no vmcnt(0) drain).
// EPI=0: f32 out; EPI=1: gelu->bf16; EPI=2: qkv split (Q,K bf16 [M,2048], V transposed)
template<int EPI, int SPLIT>
__global__ __launch_bounds__(256) void gemm_bt_kernel(
    const u16* __restrict__ A, const u16* __restrict__ W,
    float* __restrict__ Cf, u16* __restrict__ Cb, u16* __restrict__ Vt,
    int M, int N, int K)
{
  __shared__ __align__(16) u16 As[3][128 * 32];
  __shared__ __align__(16) u16 Bs[3][128 * 32];
  const int tn = N >> 7, tm = M >> 7;
  int bid = blockIdx.x;
  const int nwg = gridDim.x;
  if ((nwg & 7) == 0) bid = (bid & 7) * (nwg >> 3) + (bid >> 3);  // XCD swizzle
  const int ts = tm * tn;
  const int sK = bid / ts;
  const int tb = bid - sK * ts;
  const int bm = tb / tn, bn = tb % tn;
  const int Kc = K / SPLIT;
  const int kbeg = sK * Kc;

  const int t = threadIdx.x, l = t & 63, w = t >> 6;
  const int wr = w >> 1, wc = w & 1;
  const int m0 = bm << 7, n0 = bn << 7;
  // store-side swizzle: LDS chunk (l&3) at row (l>>2) holds global chunk (l&3)^((row>>1)&3)
  const int ssc = (((l & 3) ^ ((l >> 3) & 3)) << 3);
  const int srA = m0 + (w << 5) + (l >> 2);
  const int srB = n0 + (w << 5) + (l >> 2);
  const int ldso = (w << 10);
  const int fr = l & 15;
  // read-side: global chunk (l>>4) lives at LDS chunk (l>>4)^((R>>1)&3), (R>>1)&3 == (l>>1)&3
  const int fc8 = (((l >> 4) ^ ((l >> 1) & 3)) << 3);

  f32x4 acc[4][4];
#pragma unroll
  for (int i = 0; i < 4; ++i)
#pragma unroll
    for (int j = 0; j < 4; ++j)
#pragma unroll
      for (int e = 0; e < 4; ++e) acc[i][j][e] = 0.f;

  const u16* pa0 = A + (size_t)srA * K + kbeg + ssc;
  const u16* pa1 = A + (size_t)(srA + 16) * K + kbeg + ssc;
  const u16* pb0 = W + (size_t)srB * K + kbeg + ssc;
  const u16* pb1 = W + (size_t)(srB + 16) * K + kbeg + ssc;

#define STAGE(buf, koff)                              \
  do {                                                \
    gload_lds16(pa0 + (koff), &As[buf][ldso]);        \
    gload_lds16(pa1 + (koff), &As[buf][ldso + 512]);  \
    gload_lds16(pb0 + (koff), &Bs[buf][ldso]);        \
    gload_lds16(pb1 + (koff), &Bs[buf][ldso + 512]);  \
  } while (0)

  const int nt = Kc >> 5;
  STAGE(0, 0);
  STAGE(1, 32);
  int cur = 0;
  for (int kt = 0; kt < nt; ++kt) {
    if (kt + 2 < nt) {
      int nb = cur + 2; if (nb >= 3) nb -= 3;
      STAGE(nb, (kt + 2) << 5);
      asm volatile("s_waitcnt vmcnt(8)" ::: "memory");
    } else if (kt + 1 < nt) {
      asm volatile("s_waitcnt vmcnt(4)" ::: "memory");
    } else {
      asm volatile("s_waitcnt vmcnt(0)" ::: "memory");
    }
    __builtin_amdgcn_s_barrier();          // tile kt fully in LDS
    __builtin_amdgcn_sched_barrier(0);
    s16x8 af[4], bfr[4];
#pragma unroll
    for (int m = 0; m < 4; ++m)
      af[m] = *(const s16x8*)(&As[cur][(wr * 64 + m * 16 + fr) * 32 + fc8]);
#pragma unroll
    for (int n = 0; n < 4; ++n)
      bfr[n] = *(const s16x8*)(&Bs[cur][(wc * 64 + n * 16 + fr) * 32 + fc8]);
#pragma unroll
    for (int m = 0; m < 4; ++m)
#pragma unroll
      for (int n = 0; n < 4; ++n)
        acc[m][n] = __builtin_amdgcn_mfma_f32_16x16x32_bf16(af[m], bfr[n], acc[m][n], 0, 0, 0);
    asm volatile("s_waitcnt lgkmcnt(0)" ::: "memory");
    __builtin_amdgcn_sched_barrier(0);
    __builtin_amdgcn_s_barrier();          // reads done; buffer reusable
    cur += 1; if (cur >= 3) cur -= 3;
  }
#undef STAGE

  const int rb = m0 + wr * 64 + ((l >> 4) << 2);
  const int cb = n0 + wc * 64 + fr;
  if (SPLIT > 1) {
    float* Cp = Cf + (size_t)sK * M * N;
#pragma unroll
    for (int m = 0; m < 4; ++m)
#pragma unroll
      for (int n = 0; n < 4; ++n)
#pragma unroll
        for (int j = 0; j < 4; ++j)
          Cp[(size_t)(rb + m * 16 + j) * N + cb + n * 16] = acc[m][n][j];
  } else {
#pragma unroll
    for (int m = 0; m < 4; ++m)
#pragma unroll
      for (int n = 0; n < 4; ++n) {
        if (EPI == 2 && n0 >= 2048) {
          int cc = cb + n * 16 - 2048;
          int hh = cc >> 6, dd = cc & 63;
          int r0 = rb + m * 16;
          ushort4 ov;
          ov.x = f2bf(acc[m][n][0]); ov.y = f2bf(acc[m][n][1]);
          ov.z = f2bf(acc[m][n][2]); ov.w = f2bf(acc[m][n][3]);
          *(ushort4*)&Vt[((size_t)((r0 >> 10) * 16 + hh) * 64 + dd) * 1024 + (r0 & 1023)] = ov;
        } else {
#pragma unroll
          for (int j = 0; j < 4; ++j) {
            int r = rb + m * 16 + j;
            int c = cb + n * 16;
            float v = acc[m][n][j];
            if (EPI == 1) {
              v = 0.5f * v * (1.f + erff(v * 0.70710678118f));
              Cb[(size_t)r * N + c] = f2bf(v);
            } else if (EPI == 2) {
              Cb[(size_t)r * 2048 + c] = f2bf(v);
            } else {
              Cf[(size_t)r * N + c] = v;
            }
          }
        }
      }
  }
}

// ---------------- MFMA flash attention, causal ----------------
__global__ __launch_bounds__(256) void attn_mfma_kernel(
    const u16* __restrict__ qk, const u16* __restrict__ Vt, u16* __restrict__ out)
{
  const int h = blockIdx.y, b = blockIdx.z;
  const int qt = (h & 1) ? (15 - blockIdx.x) : blockIdx.x;
  const int t = threadIdx.x, l = t & 63, w = t >> 6;
  const int q0 = qt << 6;
  __shared__ __align__(16) u16 Ks[64 * 64];
  __shared__ __align__(16) u16 Vs[64 * 64];
  __shared__ __align__(16) u16 Ps[4][16 * 64];

  const int fr = l & 15;
  const int fg = (l >> 4) << 3;
  const int fswz = (fr & 7) << 3;

  const int qrow = q0 + w * 16 + fr;
  const size_t qbase = (size_t)(b * 1024 + qrow) * 2048 + h * 64 + fg;
  const s16x8 aq0 = *(const s16x8*)(qk + qbase);
  const s16x8 aq1 = *(const s16x8*)(qk + qbase + 32);

  f32x4 acc_o[4];
#pragma unroll
  for (int i = 0; i < 4; ++i)
#pragma unroll
    for (int e = 0; e < 4; ++e) acc_o[i][e] = 0.f;
  float m_i[4] = {-INFINITY, -INFINITY, -INFINITY, -INFINITY};
  float l_i[4] = {0.f, 0.f, 0.f, 0.f};

  const int srow = t >> 2;
  const int sc = (t & 3) << 4;
  const int c0s = sc ^ ((srow & 7) << 3);
  const int c1s = (sc + 8) ^ ((srow & 7) << 3);
  const int qrow_c = q0 + w * 16 + ((l >> 4) << 2);
  u16* Psw = &Ps[w][0];
  const int nkt = qt + 1;

  for (int kt = 0; kt < nkt; ++kt) {
    const int kb = kt << 6;
    __syncthreads();
    {
      size_t kg = (size_t)(b * 1024 + kb + srow) * 2048 + 1024 + h * 64 + sc;
      s16x8 kv0 = *(const s16x8*)(qk + kg);
      s16x8 kv1 = *(const s16x8*)(qk + kg + 8);
      size_t vg = (size_t)((b * 16 + h) * 64 + srow) * 1024 + kb + sc;
      s16x8 vv0 = *(const s16x8*)(Vt + vg);
      s16x8 vv1 = *(const s16x8*)(Vt + vg + 8);
      *(s16x8*)(Ks + srow * 64 + c0s) = kv0;
      *(s16x8*)(Ks + srow * 64 + c1s) = kv1;
      *(s16x8*)(Vs + srow * 64 + c0s) = vv0;
      *(s16x8*)(Vs + srow * 64 + c1s) = vv1;
    }
    __syncthreads();

    f32x4 s[4];
#pragma unroll
    for (int n = 0; n < 4; ++n) {
#pragma unroll
      for (int e = 0; e < 4; ++e) s[n][e] = 0.f;
      s16x8 bk0 = *(const s16x8*)(Ks + (n * 16 + fr) * 64 + (fg ^ fswz));
      s16x8 bk1 = *(const s16x8*)(Ks + (n * 16 + fr) * 64 + ((32 + fg) ^ fswz));
      s[n] = __builtin_amdgcn_mfma_f32_16x16x32_bf16(aq0, bk0, s[n], 0, 0, 0);
      s[n] = __builtin_amdgcn_mfma_f32_16x16x32_bf16(aq1, bk1, s[n], 0, 0, 0);
    }
#pragma unroll
    for (int n = 0; n < 4; ++n)
#pragma unroll
      for (int e = 0; e < 4; ++e) s[n][e] *= 0.125f;
    if (kt == qt) {
#pragma unroll
      for (int n = 0; n < 4; ++n) {
        int kc = kb + n * 16 + fr;
#pragma unroll
        for (int r = 0; r < 4; ++r)
          if (kc > qrow_c + r) s[n][r] = -INFINITY;
      }
    }

    float rm[4], fac[4];
#pragma unroll
    for (int r = 0; r < 4; ++r)
      rm[r] = fmaxf(fmaxf(s[0][r], s[1][r]), fmaxf(s[2][r], s[3][r]));
#pragma unroll
    for (int off = 1; off < 16; off <<= 1)
#pragma unroll
      for (int r = 0; r < 4; ++r) rm[r] = fmaxf(rm[r], __shfl_xor(rm[r], off));
#pragma unroll
    for (int r = 0; r < 4; ++r) {
      float mn = fmaxf(m_i[r], rm[r]);
      fac[r] = __expf(m_i[r] - mn);
      m_i[r] = mn;
    }
    float rs[4] = {0.f, 0.f, 0.f, 0.f};
    float pb[4][4];
#pragma unroll
    for (int n = 0; n < 4; ++n)
#pragma unroll
      for (int r = 0; r < 4; ++r) {
        float pv = __expf(s[n][r] - m_i[r]);
        pb[n][r] = pv;
        rs[r] += pv;
      }
#pragma unroll
    for (int off = 1; off < 16; off <<= 1)
#pragma unroll
      for (int r = 0; r < 4; ++r) rs[r] += __shfl_xor(rs[r], off);
#pragma unroll
    for (int r = 0; r < 4; ++r) l_i[r] = l_i[r] * fac[r] + rs[r];
#pragma unroll
    for (int dt = 0; dt < 4; ++dt)
#pragma unroll
      for (int r = 0; r < 4; ++r) acc_o[dt][r] *= fac[r];

#pragma unroll
    for (int n = 0; n < 4; ++n)
#pragma unroll
      for (int r = 0; r < 4; ++r) {
        int prow = ((l >> 4) << 2) + r;
        Psw[prow * 64 + ((n * 16 + fr) ^ ((prow & 7) << 3))] = f2bf(pb[n][r]);
      }
    asm volatile("s_waitcnt lgkmcnt(0)" ::: "memory");
    __builtin_amdgcn_sched_barrier(0);

    s16x8 pa0 = *(const s16x8*)(Psw + fr * 64 + (fg ^ fswz));
    s16x8 pa1 = *(const s16x8*)(Psw + fr * 64 + ((32 + fg) ^ fswz));
#pragma unroll
    for (int dt = 0; dt < 4; ++dt) {
      s16x8 bv0 = *(const s16x8*)(Vs + (dt * 16 + fr) * 64 + (fg ^ fswz));
      s16x8 bv1 = *(const s16x8*)(Vs + (dt * 16 + fr) * 64 + ((32 + fg) ^ fswz));
      acc_o[dt] = __builtin_amdgcn_mfma_f32_16x16x32_bf16(pa0, bv0, acc_o[dt], 0, 0, 0);
      acc_o[dt] = __builtin_amdgcn_mfma_f32_16x16x32_bf16(pa1, bv1, acc_o[dt], 0, 0, 0);
    }
  }

  float invl[4];
#pragma unroll
  for (int r = 0; r < 4; ++r) invl[r] = 1.f / l_i[r];
#pragma unroll
  for (int dt = 0; dt < 4; ++dt)
#pragma unroll
    for (int r = 0; r < 4; ++r) {
      size_t idx = (size_t)(b * 1024 + qrow_c + r) * 1024 + h * 64 + dt * 16 + fr;
      out[idx] = f2bf(acc_o[dt][r] * invl[r]);
    }
}

// ---------------- final depth-2 (sums 2 fc2 partials) ----------------
__global__ __launch_bounds__(256) void depth2_kernel(
    const float* __restrict__ p0, const float* __restrict__ p1,
    const float* __restrict__ mixrest,
    const float* __restrict__ beta, float* __restrict__ Hout)
{
  const size_t stride = (size_t)gridDim.x * 256;
  const size_t n4 = (size_t)BB * LL * RR * DD / 4;
  for (size_t i = (size_t)blockIdx.x * 256 + threadIdx.x; i < n4; i += stride) {
    size_t e = i * 4;
    int d = (int)(e & 1023);
    int n = (int)((e >> 10) & 3);
    size_t bl = e >> 12;
    float be = beta[bl * 4 + n];
    float4 f0 = *(const float4*)&p0[bl * 1024 + d];
    float4 f1 = *(const float4*)&p1[bl * 1024 + d];
    float4 m = ((const float4*)mixrest)[i];
    float4 o;
    o.x = be * (f0.x + f1.x) + m.x; o.y = be * (f0.y + f1.y) + m.y;
    o.z = be * (f0.z + f1.z) + m.z; o.w = be * (f0.w + f1.w) + m.w;
    ((float4*)Hout)[i] = o;
  }
}

extern "C" void kernel_launch(void* const* d_in, const int* in_sizes, int n_in,
                              void* d_out, int out_size, void* d_ws, size_t ws_size,
                              hipStream_t stream) {
  const float* H       = (const float*)d_in[0];
  const float* hc1_nw  = (const float*)d_in[1];
  const float* hc1_afn = (const float*)d_in[2];
  const float* hc1_bfn = (const float*)d_in[3];
  const float* hc1_as  = (const float*)d_in[4];
  const float* hc1_bs  = (const float*)d_in[5];
  const float* hc1_sa  = (const float*)d_in[6];
  const float* hc1_sb  = (const float*)d_in[7];
  const float* attn_nw = (const float*)d_in[8];
  const float* qkv_w   = (const float*)d_in[9];
  const float* out_w   = (const float*)d_in[10];
  const float* hc2_nw  = (const float*)d_in[11];
  const float* hc2_afn = (const float*)d_in[12];
  const float* hc2_bfn = (const float*)d_in[13];
  const float* hc2_as  = (const float*)d_in[14];
  const float* hc2_bs  = (const float*)d_in[15];
  const float* hc2_sa  = (const float*)d_in[16];
  const float* hc2_sb  = (const float*)d_in[17];
  const float* ffn_nw  = (const float*)d_in[18];
  const float* fc1_w   = (const float*)d_in[19];
  const float* fc2_w   = (const float*)d_in[20];
  float* Hout = (float*)d_out;

  char* wsp = (char*)d_ws;
  size_t off = 0;
  auto carve = [&](size_t bytes) {
    void* p = wsp + off;
    off = (off + bytes + 255) & ~(size_t)255;
    return p;
  };
  u16* wq_bf   = (u16*)carve((size_t)3072 * 1024 * 2);
  u16* wo_bf   = (u16*)carve((size_t)1024 * 1024 * 2);
  u16* w1_bf   = (u16*)carve((size_t)4096 * 1024 * 2);
  u16* w2_bf   = (u16*)carve((size_t)4096 * 1024 * 2);
  u16* xbf     = (u16*)carve((size_t)4096 * 1024 * 2);
  float* mixrest = (float*)carve((size_t)4096 * 4096 * 4);
  float* beta1 = (float*)carve((size_t)16384 * 4);
  float* beta2 = (float*)carve((size_t)16384 * 4);
  char* uregion = (char*)carve((size_t)32 * 1024 * 1024);
  u16* qk_bf   = (u16*)uregion;
  u16* Vt      = (u16*)(uregion + (size_t)16 * 1024 * 1024);
  u16* g1_bf   = (u16*)uregion;
  u16* attn_bf = (u16*)carve((size_t)4096 * 1024 * 2);
  float* parts = (float*)carve((size_t)2 * 4096 * 1024 * 4);  // 2 f32 partials
  float* part1 = parts + (size_t)4096 * 1024;

  // 1. weights -> bf16 (fused)
  cvt4_kernel<<<2048, 256, 0, stream>>>(qkv_w, out_w, fc1_w, fc2_w, wq_bf, wo_bf, w1_bf, w2_bf);
  // 2. width1 (+ pre-attn RMS)
  width_kernel<false><<<4096, 256, 0, stream>>>(H, nullptr, nullptr, nullptr, nullptr,
      hc1_nw, hc1_afn, hc1_bfn, hc1_as, hc1_bs, hc1_sa, hc1_sb, attn_nw,
      mixrest, beta1, xbf);
  // 3. qkv -> bf16 Q,K + transposed V
  gemm_bt_kernel<2, 1><<<32 * 24, 256, 0, stream>>>(xbf, wq_bf, nullptr, qk_bf, Vt, 4096, 3072, 1024);
  // 4. attention (MFMA flash)
  attn_mfma_kernel<<<dim3(16, 16, 4), 256, 0, stream>>>(qk_bf, Vt, attn_bf);
  // 5. out projection, split-K=2 -> f32 partials
  gemm_bt_kernel<0, 2><<<32 * 8 * 2, 256, 0, stream>>>(attn_bf, wo_bf, parts, nullptr, nullptr, 4096, 1024, 1024);
  // 6. depth1 + width2 (+ pre-ffn RMS)
  width_kernel<true><<<4096, 256, 0, stream>>>(nullptr, mixrest, beta1, parts, part1,
      hc2_nw, hc2_afn, hc2_bfn, hc2_as, hc2_bs, hc2_sa, hc2_sb, ffn_nw,
      mixrest, beta2, xbf);
  // 7. fc1 + gelu -> bf16
  gemm_bt_kernel<1, 1><<<32 * 32, 256, 0, stream>>>(xbf, w1_bf, nullptr, g1_bf, nullptr, 4096, 4096, 1024);
  // 8. fc2, split-K=2 -> f32 partials
  gemm_bt_kernel<0, 2><<<32 * 8 * 2, 256, 0, stream>>>(g1_bf, w2_bf, parts, nullptr, nullptr, 4096, 1024, 4096);
  // 9. depth2 -> output
  depth2_kernel<<<4096, 256, 0, stream>>>(parts, part1, mixrest, beta2, Hout);
}